// Round 1
// baseline (846.237 us; speedup 1.0000x reference)
//
#include <hip/hip_runtime.h>
#include <math.h>

#define HW 65536
#define Hdim 256
#define Wdim 256
#define Bdim 4
#define Cdim 64

__device__ __forceinline__ float lrelu(float x){ return x >= 0.f ? x : 0.1f*x; }
__device__ __forceinline__ float sigmoidf(float x){ return 1.f/(1.f+expf(-x)); }

// ---------- K0: effective weights Wri_e = Wri@Wv, Wrc_e = Wrc@Wv, biases ----------
__global__ void k0_combine(const float* __restrict__ Wv, const float* __restrict__ bv,
                           const float* __restrict__ Wri, const float* __restrict__ bri,
                           const float* __restrict__ Wrc, const float* __restrict__ brc,
                           float* __restrict__ WriE, float* __restrict__ briE,
                           float* __restrict__ WrcE, float* __restrict__ brcE){
  int idx = blockIdx.x*256 + threadIdx.x;
  if (idx < 1024){
    int j = idx>>6, c = idx&63;
    float s1=0.f, s2=0.f;
    for (int k=0;k<64;k++){ s1 = fmaf(Wri[j*64+k], Wv[k*64+c], s1); s2 = fmaf(Wrc[j*64+k], Wv[k*64+c], s2); }
    WriE[idx]=s1; WrcE[idx]=s2;
  }
  if (idx < 16){
    float s1=bri[idx], s2=brc[idx];
    for (int k=0;k<64;k++){ s1 = fmaf(Wri[idx*64+k], bv[k], s1); s2 = fmaf(Wrc[idx*64+k], bv[k], s2); }
    briE[idx]=s1; brcE[idx]=s2;
  }
}

// ---------- premask 1: mrow1[j] = lrelu(sum_e Wm1[j,e] + bm1[j]), mrow0[j]=lrelu(bm1[j]) ----------
__global__ void k_premask1(const float* __restrict__ Wm1, const float* __restrict__ bm1,
                           float* __restrict__ mrow1, float* __restrict__ mrow0){
  __shared__ float red[256];
  int j = blockIdx.x, tid = threadIdx.x;
  const float* row = Wm1 + (size_t)j*4096;
  float s=0.f;
  for (int e=tid;e<4096;e+=256) s += row[e];
  red[tid]=s; __syncthreads();
  for (int o=128;o;o>>=1){ if (tid<o) red[tid]+=red[tid+o]; __syncthreads(); }
  if (tid==0){
    float t = red[0]+bm1[j];
    mrow1[j] = lrelu(t);
    mrow0[j] = lrelu(bm1[j]);
  }
}

// ---------- premask 2: mask1[e], mask0[e] ----------
__global__ void k_premask2(const float* __restrict__ Wm2, const float* __restrict__ bm2,
                           const float* __restrict__ mrow1, const float* __restrict__ mrow0,
                           float* __restrict__ mask1, float* __restrict__ mask0){
  __shared__ float r1[256], r0[256];
  int e = blockIdx.x, tid = threadIdx.x;
  const float* row = Wm2 + (size_t)e*2048;
  float s1=0.f, s0=0.f;
  for (int j=tid;j<2048;j+=256){ float wv=row[j]; s1 = fmaf(wv, mrow1[j], s1); s0 = fmaf(wv, mrow0[j], s0); }
  r1[tid]=s1; r0[tid]=s0; __syncthreads();
  for (int o=128;o;o>>=1){ if (tid<o){ r1[tid]+=r1[tid+o]; r0[tid]+=r0[tid+o]; } __syncthreads(); }
  if (tid==0){ mask1[e]=r1[0]+bm2[e]; mask0[e]=r0[0]+bm2[e]; }
}

// ---------- transpose Wq,Wk ----------
__global__ void k_transpose(const float* __restrict__ Wq, const float* __restrict__ Wk,
                            float* __restrict__ WqT, float* __restrict__ WkT){
  int idx = blockIdx.x*256 + threadIdx.x;
  if (idx < 4096){
    int oc = idx>>6, c = idx&63;
    WqT[c*64+oc] = Wq[idx];
    WkT[c*64+oc] = Wk[idx];
  }
}

// ---------- K1: per-pixel v, xm, x_, block channel-sums ----------
__global__ __launch_bounds__(256) void k1_pw(
    const float* __restrict__ x, const float* __restrict__ Wv, const float* __restrict__ bv,
    const float* __restrict__ WriE, const float* __restrict__ briE,
    const float* __restrict__ WrcE, const float* __restrict__ brcE,
    const float* __restrict__ ln_w, const float* __restrict__ ln_b,
    float* __restrict__ v, float* __restrict__ x_, float* __restrict__ xm,
    float* __restrict__ bsum){
  __shared__ float sWv[4096], sA[1024], sB[1024];
  __shared__ float wred[4][16];
  int tid = threadIdx.x;
  for (int i=tid;i<4096;i+=256) sWv[i]=Wv[i];
  for (int i=tid;i<1024;i+=256){ sA[i]=WriE[i]; sB[i]=WrcE[i]; }
  __syncthreads();
  int b = blockIdx.x >> 8;
  int hw = ((blockIdx.x & 255) << 8) | tid;
  const float* xb = x + (((size_t)b)<<22) + hw;
  float acc[64], r1[16], rc[16];
  #pragma unroll
  for (int oc=0;oc<64;oc++) acc[oc]=0.f;
  #pragma unroll
  for (int j=0;j<16;j++){ r1[j]=0.f; rc[j]=0.f; }
  for (int c=0;c<64;c++){
    float xv = xb[((size_t)c)<<16];
    #pragma unroll
    for (int oc=0;oc<64;oc++) acc[oc] = fmaf(sWv[oc*64+c], xv, acc[oc]);
    #pragma unroll
    for (int j=0;j<16;j++){ r1[j] = fmaf(sA[j*64+c], xv, r1[j]); rc[j] = fmaf(sB[j*64+c], xv, rc[j]); }
  }
  float* vb = v + (((size_t)b)<<22) + hw;
  #pragma unroll
  for (int oc=0;oc<64;oc++) vb[((size_t)oc)<<16] = acc[oc] + bv[oc];
  // xm = mean over 16 of lrelu(r1 + briE)
  float s1=0.f;
  #pragma unroll
  for (int j=0;j<16;j++){ float t = r1[j]+briE[j]; s1 += lrelu(t); }
  xm[(((size_t)b)<<16)+hw] = s1*(1.f/16.f);
  // LN over rc
  float u=0.f;
  #pragma unroll
  for (int j=0;j<16;j++){ rc[j] += brcE[j]; u += rc[j]; }
  u *= (1.f/16.f);
  float s2=0.f;
  #pragma unroll
  for (int j=0;j<16;j++){ float d = rc[j]-u; s2 += d*d; }
  float inv = 1.0f / sqrtf(s2*(1.f/16.f) + 1e-6f);
  float xs[16];
  #pragma unroll
  for (int j=0;j<16;j++){
    float t = (rc[j]-u)*inv*ln_w[j] + ln_b[j];
    t = lrelu(t);
    xs[j]=t;
    x_[(((size_t)(b*16+j))<<16)+hw] = t;
  }
  int lane = tid & 63, wv_ = tid >> 6;
  #pragma unroll
  for (int j=0;j<16;j++){
    float val = xs[j];
    for (int o=32;o;o>>=1) val += __shfl_down(val, o, 64);
    if (lane==0) wred[wv_][j]=val;
  }
  __syncthreads();
  if (tid<16) bsum[blockIdx.x*16+tid] = wred[0][tid]+wred[1][tid]+wred[2][tid]+wred[3][tid];
}

// ---------- K2: sa = sigmoid(conv3x3(x_,Wsa)+bsa) ----------
__global__ __launch_bounds__(256) void k2_sa(const float* __restrict__ x_,
    const float* __restrict__ Wsa, const float* __restrict__ bsa, float* __restrict__ sa){
  int idx = blockIdx.x*256 + threadIdx.x;
  int b = idx>>16; int hw = idx & 65535; int h = hw>>8, wcol = hw & 255;
  float acc = bsa[0];
  for (int ch=0; ch<16; ++ch){
    const float* plane = x_ + (((size_t)(b*16+ch))<<16);
    #pragma unroll
    for (int ky=0;ky<3;ky++){
      int y = h + ky - 1;
      if ((unsigned)y >= 256u) continue;
      #pragma unroll
      for (int kx=0;kx<3;kx++){
        int xx = wcol + kx - 1;
        if ((unsigned)xx >= 256u) continue;
        acc = fmaf(Wsa[ch*9+ky*3+kx], plane[(y<<8)+xx], acc);
      }
    }
  }
  sa[idx] = sigmoidf(acc);
}

// ---------- K3: ca ----------
__global__ void k3_ca(const float* __restrict__ bsum, const float* __restrict__ Wca,
                      const float* __restrict__ bca, float* __restrict__ ca){
  __shared__ float meanx[4][16];
  int tid = threadIdx.x;
  if (tid < 64){
    int b = tid>>4, j = tid&15;
    float s=0.f;
    for (int blk=0;blk<256;blk++) s += bsum[(b*256+blk)*16 + j];
    meanx[b][j] = s*(1.f/65536.f);
  }
  __syncthreads();
  int b = tid>>6, oc = tid&63;
  float a = bca[oc];
  #pragma unroll
  for (int j=0;j<16;j++) a = fmaf(Wca[oc*16+j], meanx[b][j], a);
  ca[tid] = sigmoidf(a);
}

// ---------- K4a: per-window variance of xm ----------
__global__ void k4a_var(const float* __restrict__ xm, float* __restrict__ var){
  int t = blockIdx.x*256 + threadIdx.x; // 4096
  int b = t>>10, n = t&1023, wh = n>>5, ww = n&31;
  const float* base = xm + (((size_t)b)<<16) + (wh<<11) + (ww<<3);
  float s=0.f;
  #pragma unroll
  for (int dh=0;dh<8;dh++){
    #pragma unroll
    for (int dw=0;dw<8;dw++) s += base[(dh<<8)+dw];
  }
  float mean = s*(1.f/64.f);
  float ss=0.f;
  #pragma unroll
  for (int dh=0;dh<8;dh++){
    #pragma unroll
    for (int dw=0;dw<8;dw++){ float d = base[(dh<<8)+dw]-mean; ss += d*d; }
  }
  var[t] = ss*(1.f/63.f);
}

// ---------- K4b: rank -> sel (mask_bin) ----------
__global__ __launch_bounds__(1024) void k4b_sel(const float* __restrict__ var, float* __restrict__ sel){
  __shared__ float vs[1024];
  int b = blockIdx.x, tid = threadIdx.x;
  float mine = var[b*1024+tid];
  vs[tid]=mine; __syncthreads();
  int rank=0;
  for (int j=0;j<1024;j++){
    float o = vs[j];
    rank += (o < mine) || (o == mine && j < tid);
  }
  sel[b*1024+tid] = (rank >= 512) ? 1.f : 0.f;
}

// ---------- K6: per-window attention ----------
__global__ __launch_bounds__(256) void k6_attn(
    const float* __restrict__ x, const float* __restrict__ v, const float* __restrict__ sa,
    const float* __restrict__ sel, const float* __restrict__ mask1, const float* __restrict__ mask0,
    const float* __restrict__ WqT, const float* __restrict__ WkT,
    const float* __restrict__ bq, const float* __restrict__ bk,
    float* __restrict__ out){
  __shared__ float mx[64*65];   // masked x [p][c] (stride 64 usage), reused as scores (stride 65)
  __shared__ float vw[64*64];   // v window [p][c]
  __shared__ float qs[64*64];   // q [p][c]
  __shared__ float ks[64*65];   // k [c][p] stride 65, reused as attn_out (stride 65)
  __shared__ float saw[64];
  int tid = threadIdx.x;
  int w = blockIdx.x;
  int b = w>>10, n = w&1023, wh = n>>5, ww = n&31;
  const float* mv = (sel[w] > 0.5f) ? mask1 : mask0;
  size_t xbase = ((size_t)b)<<22;
  int pix0 = (wh<<11) + (ww<<3);
  // load: masked x and v window
  for (int i=0;i<16;i++){
    int idx = i*256 + tid;
    int p = idx & 63, c = idx >> 6;
    int gofs = ((p>>3)<<8) + (p&7);
    size_t g = xbase + (((size_t)c)<<16) + pix0 + gofs;
    float m = mv[p*64+c];
    mx[p*64+c] = x[g]*m;
    vw[p*64+c] = v[g];
  }
  if (tid < 64){
    int p = tid;
    saw[p] = sa[(((size_t)b)<<16) + pix0 + ((p>>3)<<8) + (p&7)];
  }
  __syncthreads();
  int oc = tid & 63, pg = tid >> 6;
  // q, k projections
  {
    float aq[16], ak[16];
    float bqv = bq[oc], bkv = bk[oc];
    #pragma unroll
    for (int i=0;i<16;i++){ aq[i]=bqv; ak[i]=bkv; }
    for (int c=0;c<64;c++){
      float wq = WqT[c*64+oc], wk = WkT[c*64+oc];
      #pragma unroll
      for (int i=0;i<16;i++){
        float xm_ = mx[(pg*16+i)*64 + c];
        aq[i] = fmaf(xm_, wq, aq[i]);
        ak[i] = fmaf(xm_, wk, ak[i]);
      }
    }
    #pragma unroll
    for (int i=0;i<16;i++){
      int p = pg*16+i;
      qs[p*64+oc] = aq[i];
      ks[oc*65+p] = ak[i];
    }
  }
  __syncthreads();
  // scores into mx with stride 65
  {
    int p2 = oc;
    float ss[16];
    #pragma unroll
    for (int i=0;i<16;i++) ss[i]=0.f;
    for (int c=0;c<64;c++){
      float kv = ks[c*65+p2];
      #pragma unroll
      for (int i=0;i<16;i++) ss[i] = fmaf(qs[(pg*16+i)*64 + c], kv, ss[i]);
    }
    #pragma unroll
    for (int i=0;i<16;i++) mx[(pg*16+i)*65 + p2] = ss[i];
  }
  __syncthreads();
  // softmax rows (threads 0..63)
  if (tid < 64){
    int r = tid;
    float mmax = -1e30f;
    for (int j=0;j<64;j++) mmax = fmaxf(mmax, mx[r*65+j]);
    float ssum = 0.f;
    for (int j=0;j<64;j++){ float e = expf(mx[r*65+j]-mmax); mx[r*65+j]=e; ssum += e; }
    float inv = 1.f/ssum;
    for (int j=0;j<64;j++) mx[r*65+j] *= inv;
  }
  __syncthreads();
  // f = attn @ (vw*m); out = f + vw*saw*(1-m) -> ks (stride 65)
  {
    int c = oc;
    float facc[16];
    #pragma unroll
    for (int i=0;i<16;i++) facc[i]=0.f;
    for (int p2=0;p2<64;p2++){
      float v1 = vw[p2*64+c]*mv[p2*64+c];
      #pragma unroll
      for (int i=0;i<16;i++) facc[i] = fmaf(mx[(pg*16+i)*65 + p2], v1, facc[i]);
    }
    #pragma unroll
    for (int i=0;i<16;i++){
      int p = pg*16+i;
      float m_pc = mv[p*64+c];
      ks[p*65+c] = facc[i] + vw[p*64+c]*saw[p]*(1.f-m_pc);
    }
  }
  __syncthreads();
  // cooperative coalesced store
  for (int i=0;i<16;i++){
    int idx = i*256 + tid;
    int p = idx & 63, c = idx >> 6;
    int gofs = ((p>>3)<<8) + (p&7);
    out[xbase + (((size_t)c)<<16) + pix0 + gofs] = ks[p*65+c];
  }
}

// ---------- K7a: depthwise 3x3 pad1 ----------
__global__ __launch_bounds__(256) void k7a_dw1(const float* __restrict__ in,
    const float* __restrict__ Wd1, const float* __restrict__ bd1, float* __restrict__ c1){
  int idx = blockIdx.x*256 + threadIdx.x;
  int wcol = idx & 255, h = (idx>>8) & 255, ch = (idx>>16) & 63;
  const float* wd = Wd1 + ch*9;
  int planebase = idx & 0x7FFF0000; // (b*64+ch)*65536 (fits: max 16M)
  float acc = bd1[ch];
  #pragma unroll
  for (int ky=0;ky<3;ky++){
    int y = h + ky - 1;
    if ((unsigned)y >= 256u) continue;
    #pragma unroll
    for (int kx=0;kx<3;kx++){
      int xx = wcol + kx - 1;
      if ((unsigned)xx >= 256u) continue;
      acc = fmaf(wd[ky*3+kx], in[planebase + (y<<8) + xx], acc);
    }
  }
  c1[idx] = acc;
}

// ---------- K7b: depthwise 3x3 dil2 pad2, gelu*ca + residual (in-place on outbuf) ----------
__global__ __launch_bounds__(256) void k7b_dw2(const float* __restrict__ c1,
    const float* __restrict__ Wd2, const float* __restrict__ bd2,
    const float* __restrict__ ca, float* __restrict__ outbuf){
  int idx = blockIdx.x*256 + threadIdx.x;
  int wcol = idx & 255, h = (idx>>8) & 255;
  const float* wd = Wd2 + ((idx>>16)&63)*9;
  int planebase = idx & 0x7FFF0000;
  float acc = bd2[(idx>>16)&63];
  #pragma unroll
  for (int ky=0;ky<3;ky++){
    int y = h + 2*ky - 2;
    if ((unsigned)y >= 256u) continue;
    #pragma unroll
    for (int kx=0;kx<3;kx++){
      int xx = wcol + 2*kx - 2;
      if ((unsigned)xx >= 256u) continue;
      acc = fmaf(wd[ky*3+kx], c1[planebase + (y<<8) + xx], acc);
    }
  }
  float g = 0.5f*acc*(1.f + erff(acc*0.70710678118654752f));
  outbuf[idx] = fmaf(g, ca[idx>>16], outbuf[idx]);
}

// ---------- K7c: final 1x1 conv ----------
__global__ __launch_bounds__(256) void k7c_proj(const float* __restrict__ in,
    const float* __restrict__ Wo, const float* __restrict__ bo, float* __restrict__ out){
  __shared__ float sW[4096];
  for (int i=threadIdx.x;i<4096;i+=256) sW[i]=Wo[i];
  __syncthreads();
  int b = blockIdx.x >> 8;
  int hw = ((blockIdx.x & 255) << 8) | threadIdx.x;
  const float* pb = in + (((size_t)b)<<22) + hw;
  float acc[64];
  #pragma unroll
  for (int oc=0;oc<64;oc++) acc[oc]=bo[oc];
  for (int c=0;c<64;c++){
    float xv = pb[((size_t)c)<<16];
    #pragma unroll
    for (int oc=0;oc<64;oc++) acc[oc] = fmaf(sW[oc*64+c], xv, acc[oc]);
  }
  float* ob = out + (((size_t)b)<<22) + hw;
  #pragma unroll
  for (int oc=0;oc<64;oc++) ob[((size_t)oc)<<16] = acc[oc];
}

extern "C" void kernel_launch(void* const* d_in, const int* in_sizes, int n_in,
                              void* d_out, int out_size, void* d_ws, size_t ws_size,
                              hipStream_t stream) {
  const float* x    = (const float*)d_in[0];
  const float* Wv   = (const float*)d_in[1];
  const float* bv   = (const float*)d_in[2];
  const float* Wri  = (const float*)d_in[3];
  const float* bri  = (const float*)d_in[4];
  const float* Wrc  = (const float*)d_in[5];
  const float* brc  = (const float*)d_in[6];
  const float* ln_w = (const float*)d_in[7];
  const float* ln_b = (const float*)d_in[8];
  const float* Wca  = (const float*)d_in[9];
  const float* bca  = (const float*)d_in[10];
  const float* Wsa  = (const float*)d_in[11];
  const float* bsa  = (const float*)d_in[12];
  const float* Wm1  = (const float*)d_in[13];
  const float* bm1  = (const float*)d_in[14];
  const float* Wm2  = (const float*)d_in[15];
  const float* bm2  = (const float*)d_in[16];
  const float* Wq   = (const float*)d_in[17];
  const float* bq   = (const float*)d_in[18];
  const float* Wk   = (const float*)d_in[19];
  const float* bk   = (const float*)d_in[20];
  const float* Wd1  = (const float*)d_in[21];
  const float* bd1  = (const float*)d_in[22];
  const float* Wd2  = (const float*)d_in[23];
  const float* bd2  = (const float*)d_in[24];
  const float* Wo   = (const float*)d_in[25];
  const float* bo   = (const float*)d_in[26];
  float* out = (float*)d_out;

  float* ws = (float*)d_ws;
  float* v_buf   = ws;                    // 16777216
  float* out_buf = v_buf + 16777216;      // 16777216
  float* x_buf   = out_buf + 16777216;    // 4194304
  float* xm_buf  = x_buf + 4194304;       // 262144
  float* sa_buf  = xm_buf + 262144;       // 262144
  float* bsum    = sa_buf + 262144;       // 16384
  float* ca_buf  = bsum + 16384;          // 256
  float* var_buf = ca_buf + 256;          // 4096
  float* sel_buf = var_buf + 4096;        // 4096
  float* mrow1   = sel_buf + 4096;        // 2048
  float* mrow0   = mrow1 + 2048;          // 2048
  float* mask1   = mrow0 + 2048;          // 4096
  float* mask0   = mask1 + 4096;          // 4096
  float* WqT     = mask0 + 4096;          // 4096
  float* WkT     = WqT + 4096;            // 4096
  float* WriE    = WkT + 4096;            // 1024
  float* WrcE    = WriE + 1024;           // 1024
  float* briE    = WrcE + 1024;           // 16
  float* brcE    = briE + 16;             // 16
  float* c1_buf  = v_buf;                 // reuse (v dead after k6)

  k0_combine<<<4,256,0,stream>>>(Wv,bv,Wri,bri,Wrc,brc,WriE,briE,WrcE,brcE);
  k_premask1<<<2048,256,0,stream>>>(Wm1,bm1,mrow1,mrow0);
  k_premask2<<<4096,256,0,stream>>>(Wm2,bm2,mrow1,mrow0,mask1,mask0);
  k_transpose<<<16,256,0,stream>>>(Wq,Wk,WqT,WkT);
  k1_pw<<<1024,256,0,stream>>>(x,Wv,bv,WriE,briE,WrcE,brcE,ln_w,ln_b,v_buf,x_buf,xm_buf,bsum);
  k2_sa<<<1024,256,0,stream>>>(x_buf,Wsa,bsa,sa_buf);
  k3_ca<<<1,256,0,stream>>>(bsum,Wca,bca,ca_buf);
  k4a_var<<<16,256,0,stream>>>(xm_buf,var_buf);
  k4b_sel<<<4,1024,0,stream>>>(var_buf,sel_buf);
  k6_attn<<<4096,256,0,stream>>>(x,v_buf,sa_buf,sel_buf,mask1,mask0,WqT,WkT,bq,bk,out_buf);
  k7a_dw1<<<65536,256,0,stream>>>(out_buf,Wd1,bd1,c1_buf);
  k7b_dw2<<<65536,256,0,stream>>>(c1_buf,Wd2,bd2,ca_buf,out_buf);
  k7c_proj<<<1024,256,0,stream>>>(out_buf,Wo,bo,out);
}

// Round 2
// 782.601 us; speedup vs baseline: 1.0813x; 1.0813x over previous
//
#include <hip/hip_runtime.h>
#include <math.h>

__device__ __forceinline__ float lrelu(float x){ return x >= 0.f ? x : 0.1f*x; }
__device__ __forceinline__ float sigmoidf(float x){ return 1.f/(1.f+expf(-x)); }

// ---------- K0: effective weights WriE = Wri@Wv, WrcE = Wrc@Wv, biases ----------
__global__ void k0_combine(const float* __restrict__ Wv, const float* __restrict__ bv,
                           const float* __restrict__ Wri, const float* __restrict__ bri,
                           const float* __restrict__ Wrc, const float* __restrict__ brc,
                           float* __restrict__ WriE, float* __restrict__ briE,
                           float* __restrict__ WrcE, float* __restrict__ brcE){
  int idx = blockIdx.x*256 + threadIdx.x;
  if (idx < 1024){
    int j = idx>>6, c = idx&63;
    float s1=0.f, s2=0.f;
    for (int k=0;k<64;k++){ s1 = fmaf(Wri[j*64+k], Wv[k*64+c], s1); s2 = fmaf(Wrc[j*64+k], Wv[k*64+c], s2); }
    WriE[idx]=s1; WrcE[idx]=s2;
  }
  if (idx < 16){
    float s1=bri[idx], s2=brc[idx];
    for (int k=0;k<64;k++){ s1 = fmaf(Wri[idx*64+k], bv[k], s1); s2 = fmaf(Wrc[idx*64+k], bv[k], s2); }
    briE[idx]=s1; brcE[idx]=s2;
  }
}

// ---------- prep: transposed weight blobs for scalar-uniform access ----------
// WT[c*96 + 0..63]  = Wv[oc][c]
// WT[c*96 + 64..79] = WriE[j][c]
// WT[c*96 + 80..95] = WrcE[j][c]
// WoT[c*64 + oc]    = Wo[oc][c]
// Wqk[(c*64+oc)*2 + {0,1}] = {Wq[oc][c], Wk[oc][c]}
__global__ void k_prep(const float* __restrict__ Wq, const float* __restrict__ Wk,
                       const float* __restrict__ Wo, const float* __restrict__ Wv,
                       const float* __restrict__ WriE, const float* __restrict__ WrcE,
                       float* __restrict__ Wqk, float* __restrict__ WoT, float* __restrict__ WT){
  int idx = blockIdx.x*256 + threadIdx.x;
  if (idx < 4096){
    int oc = idx>>6, c = idx&63;
    Wqk[((c<<6)|oc)*2+0] = Wq[idx];
    Wqk[((c<<6)|oc)*2+1] = Wk[idx];
    WoT[(c<<6)|oc] = Wo[idx];
    WT[c*96 + oc] = Wv[idx];
  } else if (idx < 6144){
    int t = idx - 4096;        // 0..2047
    int j = (t>>6) & 15, c = t & 63;
    if (t < 1024) WT[c*96 + 64 + j] = WriE[j*64+c];
    else          WT[c*96 + 80 + j] = WrcE[j*64+c];
  }
}

// ---------- premask 1 ----------
__global__ void k_premask1(const float* __restrict__ Wm1, const float* __restrict__ bm1,
                           float* __restrict__ mrow1, float* __restrict__ mrow0){
  __shared__ float red[256];
  int j = blockIdx.x, tid = threadIdx.x;
  const float* row = Wm1 + (size_t)j*4096;
  float s=0.f;
  for (int e=tid;e<4096;e+=256) s += row[e];
  red[tid]=s; __syncthreads();
  for (int o=128;o;o>>=1){ if (tid<o) red[tid]+=red[tid+o]; __syncthreads(); }
  if (tid==0){
    float t = red[0]+bm1[j];
    mrow1[j] = lrelu(t);
    mrow0[j] = lrelu(bm1[j]);
  }
}

// ---------- premask 2: mask1/mask0 + transposed copies ----------
__global__ void k_premask2(const float* __restrict__ Wm2, const float* __restrict__ bm2,
                           const float* __restrict__ mrow1, const float* __restrict__ mrow0,
                           float* __restrict__ mask1, float* __restrict__ mask0,
                           float* __restrict__ mask1T, float* __restrict__ mask0T){
  __shared__ float r1[256], r0[256];
  int e = blockIdx.x, tid = threadIdx.x;
  const float* row = Wm2 + (size_t)e*2048;
  float s1=0.f, s0=0.f;
  for (int j=tid;j<2048;j+=256){ float wv=row[j]; s1 = fmaf(wv, mrow1[j], s1); s0 = fmaf(wv, mrow0[j], s0); }
  r1[tid]=s1; r0[tid]=s0; __syncthreads();
  for (int o=128;o;o>>=1){ if (tid<o){ r1[tid]+=r1[tid+o]; r0[tid]+=r0[tid+o]; } __syncthreads(); }
  if (tid==0){
    float m1 = r1[0]+bm2[e], m0 = r0[0]+bm2[e];
    mask1[e]=m1; mask0[e]=m0;
    int p = e>>6, c = e&63;
    mask1T[(c<<6)|p]=m1; mask0T[(c<<6)|p]=m0;
  }
}

// ---------- K1: per-pixel v, xm, x_, block channel-sums (scalar-uniform weights) ----------
__global__ __launch_bounds__(256) void k1_pw(
    const float* __restrict__ x, const float* __restrict__ WT,
    const float* __restrict__ bv,
    const float* __restrict__ briE, const float* __restrict__ brcE,
    const float* __restrict__ ln_w, const float* __restrict__ ln_b,
    float* __restrict__ v, float* __restrict__ x_, float* __restrict__ xm,
    float* __restrict__ bsum){
  __shared__ float wred[4][16];
  int tid = threadIdx.x;
  int b = blockIdx.x >> 8;
  int hw = ((blockIdx.x & 255) << 8) | tid;
  const float* xb = x + (((size_t)b)<<22) + hw;
  float acc[64], r1[16], rc[16];
  #pragma unroll
  for (int oc=0;oc<64;oc++) acc[oc]=0.f;
  #pragma unroll
  for (int j=0;j<16;j++){ r1[j]=0.f; rc[j]=0.f; }
  for (int c=0;c<64;c++){
    float xv = xb[((size_t)c)<<16];
    const float* wrow = WT + c*96;
    #pragma unroll
    for (int oc=0;oc<64;oc++) acc[oc] = fmaf(wrow[oc], xv, acc[oc]);
    #pragma unroll
    for (int j=0;j<16;j++){ r1[j] = fmaf(wrow[64+j], xv, r1[j]); rc[j] = fmaf(wrow[80+j], xv, rc[j]); }
  }
  float* vb = v + (((size_t)b)<<22) + hw;
  #pragma unroll
  for (int oc=0;oc<64;oc++) vb[((size_t)oc)<<16] = acc[oc] + bv[oc];
  float s1=0.f;
  #pragma unroll
  for (int j=0;j<16;j++){ float t = r1[j]+briE[j]; s1 += lrelu(t); }
  xm[(((size_t)b)<<16)+hw] = s1*(1.f/16.f);
  float u=0.f;
  #pragma unroll
  for (int j=0;j<16;j++){ rc[j] += brcE[j]; u += rc[j]; }
  u *= (1.f/16.f);
  float s2=0.f;
  #pragma unroll
  for (int j=0;j<16;j++){ float d = rc[j]-u; s2 += d*d; }
  float inv = 1.0f / sqrtf(s2*(1.f/16.f) + 1e-6f);
  float xs[16];
  #pragma unroll
  for (int j=0;j<16;j++){
    float t = (rc[j]-u)*inv*ln_w[j] + ln_b[j];
    t = lrelu(t);
    xs[j]=t;
    x_[(((size_t)(b*16+j))<<16)+hw] = t;
  }
  int lane = tid & 63, wv_ = tid >> 6;
  #pragma unroll
  for (int j=0;j<16;j++){
    float val = xs[j];
    for (int o=32;o;o>>=1) val += __shfl_down(val, o, 64);
    if (lane==0) wred[wv_][j]=val;
  }
  __syncthreads();
  if (tid<16) bsum[blockIdx.x*16+tid] = wred[0][tid]+wred[1][tid]+wred[2][tid]+wred[3][tid];
}

// ---------- K2: sa = sigmoid(conv3x3(x_,Wsa)+bsa) ----------
__global__ __launch_bounds__(256) void k2_sa(const float* __restrict__ x_,
    const float* __restrict__ Wsa, const float* __restrict__ bsa, float* __restrict__ sa){
  int idx = blockIdx.x*256 + threadIdx.x;
  int b = idx>>16; int hw = idx & 65535; int h = hw>>8, wcol = hw & 255;
  float acc = bsa[0];
  for (int ch=0; ch<16; ++ch){
    const float* plane = x_ + (((size_t)(b*16+ch))<<16);
    #pragma unroll
    for (int ky=0;ky<3;ky++){
      int y = h + ky - 1;
      if ((unsigned)y >= 256u) continue;
      #pragma unroll
      for (int kx=0;kx<3;kx++){
        int xx = wcol + kx - 1;
        if ((unsigned)xx >= 256u) continue;
        acc = fmaf(Wsa[ch*9+ky*3+kx], plane[(y<<8)+xx], acc);
      }
    }
  }
  sa[idx] = sigmoidf(acc);
}

// ---------- K3: ca ----------
__global__ void k3_ca(const float* __restrict__ bsum, const float* __restrict__ Wca,
                      const float* __restrict__ bca, float* __restrict__ ca){
  __shared__ float meanx[4][16];
  int tid = threadIdx.x;
  if (tid < 64){
    int b = tid>>4, j = tid&15;
    float s=0.f;
    for (int blk=0;blk<256;blk++) s += bsum[(b*256+blk)*16 + j];
    meanx[b][j] = s*(1.f/65536.f);
  }
  __syncthreads();
  int b = tid>>6, oc = tid&63;
  float a = bca[oc];
  #pragma unroll
  for (int j=0;j<16;j++) a = fmaf(Wca[oc*16+j], meanx[b][j], a);
  ca[tid] = sigmoidf(a);
}

// ---------- K4a: per-window variance of xm ----------
__global__ void k4a_var(const float* __restrict__ xm, float* __restrict__ var){
  int t = blockIdx.x*256 + threadIdx.x; // 4096
  int b = t>>10, n = t&1023, wh = n>>5, ww = n&31;
  const float* base = xm + (((size_t)b)<<16) + (wh<<11) + (ww<<3);
  float s=0.f;
  #pragma unroll
  for (int dh=0;dh<8;dh++){
    #pragma unroll
    for (int dw=0;dw<8;dw++) s += base[(dh<<8)+dw];
  }
  float mean = s*(1.f/64.f);
  float ss=0.f;
  #pragma unroll
  for (int dh=0;dh<8;dh++){
    #pragma unroll
    for (int dw=0;dw<8;dw++){ float d = base[(dh<<8)+dw]-mean; ss += d*d; }
  }
  var[t] = ss*(1.f/63.f);
}

// ---------- K4b: rank -> sel ----------
__global__ __launch_bounds__(1024) void k4b_sel(const float* __restrict__ var, float* __restrict__ sel){
  __shared__ float vs[1024];
  int b = blockIdx.x, tid = threadIdx.x;
  float mine = var[b*1024+tid];
  vs[tid]=mine; __syncthreads();
  int rank=0;
  for (int j=0;j<1024;j++){
    float o = vs[j];
    rank += (o < mine) || (o == mine && j < tid);
  }
  sel[b*1024+tid] = (rank >= 512) ? 1.f : 0.f;
}

// ---------- K6: per-window attention (stride-65 LDS, reg softmax, 3 blocks/CU) ----------
__global__ __launch_bounds__(256) void k6_attn(
    const float* __restrict__ x, const float* __restrict__ v, const float* __restrict__ sa,
    const float* __restrict__ sel,
    const float* __restrict__ mask1T, const float* __restrict__ mask0T,
    const float* __restrict__ Wqk,
    const float* __restrict__ bq, const float* __restrict__ bk,
    float* __restrict__ out){
  __shared__ float mx[64*65];   // masked x -> q -> attn
  __shared__ float vm[64*65];   // v*m
  __shared__ float ks[64*65];   // k [c][p] -> attn_out [p][c]
  __shared__ float saw[64];
  int tid = threadIdx.x;
  // bijective XCD swizzle: 4096 = 8 * 512
  int wg = ((blockIdx.x & 7) << 9) | (blockIdx.x >> 3);
  int b = wg >> 10, n = wg & 1023, wh = n >> 5, ww = n & 31;
  const float* mT = (sel[wg] > 0.5f) ? mask1T : mask0T;
  size_t xbase = ((size_t)b) << 22;
  int pix0 = (wh << 11) | (ww << 3);
  for (int i=0;i<16;i++){
    int idx = (i<<8) + tid;
    int p = idx & 63, c = idx >> 6;
    int gofs = ((p>>3)<<8) | (p&7);
    size_t g = xbase + (((size_t)c)<<16) + pix0 + gofs;
    float m = mT[(c<<6)|p];
    mx[p*65+c] = x[g]*m;
    vm[p*65+c] = v[g]*m;
  }
  if (tid < 64) saw[tid] = sa[(((size_t)b)<<16) + pix0 + ((tid>>3)<<8) + (tid&7)];
  __syncthreads();
  int oc = tid & 63, pg = tid >> 6;
  int r0 = pg << 4;
  // q,k projection into registers
  float aq[16], ak[16];
  {
    float bqv = bq[oc], bkv = bk[oc];
    #pragma unroll
    for (int i=0;i<16;i++){ aq[i]=bqv; ak[i]=bkv; }
    for (int c=0;c<64;c++){
      float2 wp = *(const float2*)&Wqk[(size_t)((c<<6)|oc)*2];
      #pragma unroll
      for (int i=0;i<16;i++){
        float xmv = mx[(r0+i)*65 + c];
        aq[i] = fmaf(xmv, wp.x, aq[i]);
        ak[i] = fmaf(xmv, wp.y, ak[i]);
      }
    }
  }
  __syncthreads();          // all mx reads done
  #pragma unroll
  for (int i=0;i<16;i++){
    mx[(r0+i)*65 + oc] = aq[i];     // q overwrites masked-x
    ks[oc*65 + r0 + i] = ak[i];     // k transposed [c][p]
  }
  __syncthreads();
  // scores (regs) + wave-parallel softmax
  float ss[16];
  {
    #pragma unroll
    for (int i=0;i<16;i++) ss[i]=0.f;
    int p2 = oc;
    for (int c=0;c<64;c++){
      float kv = ks[c*65 + p2];
      #pragma unroll
      for (int i=0;i<16;i++) ss[i] = fmaf(mx[(r0+i)*65 + c], kv, ss[i]);
    }
    #pragma unroll
    for (int i=0;i<16;i++){
      float mmax = ss[i];
      for (int off=32; off; off>>=1) mmax = fmaxf(mmax, __shfl_xor(mmax, off));
      float e = expf(ss[i]-mmax);
      float s = e;
      for (int off=32; off; off>>=1) s += __shfl_xor(s, off);
      ss[i] = e / s;
    }
  }
  __syncthreads();          // all q reads done
  #pragma unroll
  for (int i=0;i<16;i++) mx[(r0+i)*65 + oc] = ss[i];   // attn overwrites q
  __syncthreads();
  // AV
  float facc[16];
  #pragma unroll
  for (int i=0;i<16;i++) facc[i]=0.f;
  for (int p2=0;p2<64;p2++){
    float vv = vm[p2*65 + oc];
    #pragma unroll
    for (int i=0;i<16;i++) facc[i] = fmaf(mx[(r0+i)*65 + p2], vv, facc[i]);
  }
  #pragma unroll
  for (int i=0;i<16;i++) ks[(r0+i)*65 + oc] = facc[i];
  __syncthreads();
  // store: out = f + sa*(v - v*m)
  for (int i=0;i<16;i++){
    int idx = (i<<8) + tid;
    int p = idx & 63, c = idx >> 6;
    int gofs = ((p>>3)<<8) | (p&7);
    size_t g = xbase + (((size_t)c)<<16) + pix0 + gofs;
    out[g] = ks[p*65+c] + saw[p]*(v[g] - vm[p*65+c]);
  }
}

// ---------- K7a: depthwise 3x3 pad1 ----------
__global__ __launch_bounds__(256) void k7a_dw1(const float* __restrict__ in,
    const float* __restrict__ Wd1, const float* __restrict__ bd1, float* __restrict__ c1){
  int idx = blockIdx.x*256 + threadIdx.x;
  int wcol = idx & 255, h = (idx>>8) & 255, ch = (idx>>16) & 63;
  const float* wd = Wd1 + ch*9;
  int planebase = idx & 0x7FFF0000;
  float acc = bd1[ch];
  #pragma unroll
  for (int ky=0;ky<3;ky++){
    int y = h + ky - 1;
    if ((unsigned)y >= 256u) continue;
    #pragma unroll
    for (int kx=0;kx<3;kx++){
      int xx = wcol + kx - 1;
      if ((unsigned)xx >= 256u) continue;
      acc = fmaf(wd[ky*3+kx], in[planebase + (y<<8) + xx], acc);
    }
  }
  c1[idx] = acc;
}

// ---------- K7b: depthwise 3x3 dil2 pad2, gelu*ca + residual ----------
__global__ __launch_bounds__(256) void k7b_dw2(const float* __restrict__ c1,
    const float* __restrict__ Wd2, const float* __restrict__ bd2,
    const float* __restrict__ ca, float* __restrict__ outbuf){
  int idx = blockIdx.x*256 + threadIdx.x;
  int wcol = idx & 255, h = (idx>>8) & 255;
  const float* wd = Wd2 + ((idx>>16)&63)*9;
  int planebase = idx & 0x7FFF0000;
  float acc = bd2[(idx>>16)&63];
  #pragma unroll
  for (int ky=0;ky<3;ky++){
    int y = h + 2*ky - 2;
    if ((unsigned)y >= 256u) continue;
    #pragma unroll
    for (int kx=0;kx<3;kx++){
      int xx = wcol + 2*kx - 2;
      if ((unsigned)xx >= 256u) continue;
      acc = fmaf(wd[ky*3+kx], c1[planebase + (y<<8) + xx], acc);
    }
  }
  float g = 0.5f*acc*(1.f + erff(acc*0.70710678118654752f));
  outbuf[idx] = fmaf(g, ca[idx>>16], outbuf[idx]);
}

// ---------- K7c: final 1x1 conv (scalar-uniform weights) ----------
__global__ __launch_bounds__(256) void k7c_proj(const float* __restrict__ in,
    const float* __restrict__ WoT, const float* __restrict__ bo, float* __restrict__ out){
  int b = blockIdx.x >> 8;
  int hw = ((blockIdx.x & 255) << 8) | threadIdx.x;
  const float* pb = in + (((size_t)b)<<22) + hw;
  float acc[64];
  #pragma unroll
  for (int oc=0;oc<64;oc++) acc[oc]=bo[oc];
  for (int c=0;c<64;c++){
    float xv = pb[((size_t)c)<<16];
    const float* wrow = WoT + (c<<6);
    #pragma unroll
    for (int oc=0;oc<64;oc++) acc[oc] = fmaf(wrow[oc], xv, acc[oc]);
  }
  float* ob = out + (((size_t)b)<<22) + hw;
  #pragma unroll
  for (int oc=0;oc<64;oc++) ob[((size_t)oc)<<16] = acc[oc];
}

extern "C" void kernel_launch(void* const* d_in, const int* in_sizes, int n_in,
                              void* d_out, int out_size, void* d_ws, size_t ws_size,
                              hipStream_t stream) {
  const float* x    = (const float*)d_in[0];
  const float* Wv   = (const float*)d_in[1];
  const float* bv   = (const float*)d_in[2];
  const float* Wri  = (const float*)d_in[3];
  const float* bri  = (const float*)d_in[4];
  const float* Wrc  = (const float*)d_in[5];
  const float* brc  = (const float*)d_in[6];
  const float* ln_w = (const float*)d_in[7];
  const float* ln_b = (const float*)d_in[8];
  const float* Wca  = (const float*)d_in[9];
  const float* bca  = (const float*)d_in[10];
  const float* Wsa  = (const float*)d_in[11];
  const float* bsa  = (const float*)d_in[12];
  const float* Wm1  = (const float*)d_in[13];
  const float* bm1  = (const float*)d_in[14];
  const float* Wm2  = (const float*)d_in[15];
  const float* bm2  = (const float*)d_in[16];
  const float* Wq   = (const float*)d_in[17];
  const float* bq   = (const float*)d_in[18];
  const float* Wk   = (const float*)d_in[19];
  const float* bk   = (const float*)d_in[20];
  const float* Wd1  = (const float*)d_in[21];
  const float* bd1  = (const float*)d_in[22];
  const float* Wd2  = (const float*)d_in[23];
  const float* bd2  = (const float*)d_in[24];
  const float* Wo   = (const float*)d_in[25];
  const float* bo   = (const float*)d_in[26];
  float* out = (float*)d_out;

  float* ws = (float*)d_ws;
  float* v_buf   = ws;                    // 16777216
  float* out_buf = v_buf + 16777216;      // 16777216
  float* x_buf   = out_buf + 16777216;    // 4194304
  float* xm_buf  = x_buf + 4194304;       // 262144
  float* sa_buf  = xm_buf + 262144;       // 262144
  float* bsum    = sa_buf + 262144;       // 16384
  float* ca_buf  = bsum + 16384;          // 256
  float* var_buf = ca_buf + 256;          // 4096
  float* sel_buf = var_buf + 4096;        // 4096
  float* mrow1   = sel_buf + 4096;        // 2048
  float* mrow0   = mrow1 + 2048;          // 2048
  float* mask1   = mrow0 + 2048;          // 4096
  float* mask0   = mask1 + 4096;          // 4096
  float* mask1T  = mask0 + 4096;          // 4096
  float* mask0T  = mask1T + 4096;         // 4096
  float* Wqk     = mask0T + 4096;         // 8192
  float* WoT     = Wqk + 8192;            // 4096
  float* WT      = WoT + 4096;            // 6144
  float* WriE    = WT + 6144;             // 1024
  float* WrcE    = WriE + 1024;           // 1024
  float* briE    = WrcE + 1024;           // 16
  float* brcE    = briE + 16;             // 16
  float* c1_buf  = v_buf;                 // reuse (v dead after k6... k7a runs after k6)

  k0_combine<<<4,256,0,stream>>>(Wv,bv,Wri,bri,Wrc,brc,WriE,briE,WrcE,brcE);
  k_prep<<<24,256,0,stream>>>(Wq,Wk,Wo,Wv,WriE,WrcE,Wqk,WoT,WT);
  k_premask1<<<2048,256,0,stream>>>(Wm1,bm1,mrow1,mrow0);
  k_premask2<<<4096,256,0,stream>>>(Wm2,bm2,mrow1,mrow0,mask1,mask0,mask1T,mask0T);
  k1_pw<<<1024,256,0,stream>>>(x,WT,bv,briE,brcE,ln_w,ln_b,v_buf,x_buf,xm_buf,bsum);
  k2_sa<<<1024,256,0,stream>>>(x_buf,Wsa,bsa,sa_buf);
  k3_ca<<<1,256,0,stream>>>(bsum,Wca,bca,ca_buf);
  k4a_var<<<16,256,0,stream>>>(xm_buf,var_buf);
  k4b_sel<<<4,1024,0,stream>>>(var_buf,sel_buf);
  k6_attn<<<4096,256,0,stream>>>(x,v_buf,sa_buf,sel_buf,mask1T,mask0T,Wqk,bq,bk,out_buf);
  k7a_dw1<<<65536,256,0,stream>>>(out_buf,Wd1,bd1,c1_buf);
  k7b_dw2<<<65536,256,0,stream>>>(c1_buf,Wd2,bd2,ca_buf,out_buf);
  k7c_proj<<<1024,256,0,stream>>>(out_buf,WoT,bo,out);
}

// Round 4
// 594.332 us; speedup vs baseline: 1.4238x; 1.3168x over previous
//
#include <hip/hip_runtime.h>
#include <math.h>

__device__ __forceinline__ float lrelu(float x){ return x >= 0.f ? x : 0.1f*x; }
__device__ __forceinline__ float sigmoidf(float x){ return 1.f/(1.f+expf(-x)); }

// ---------- K0: effective weights WriE = Wri@Wv, WrcE = Wrc@Wv, biases ----------
__global__ void k0_combine(const float* __restrict__ Wv, const float* __restrict__ bv,
                           const float* __restrict__ Wri, const float* __restrict__ bri,
                           const float* __restrict__ Wrc, const float* __restrict__ brc,
                           float* __restrict__ WriE, float* __restrict__ briE,
                           float* __restrict__ WrcE, float* __restrict__ brcE){
  int idx = blockIdx.x*256 + threadIdx.x;
  if (idx < 1024){
    int j = idx>>6, c = idx&63;
    float s1=0.f, s2=0.f;
    for (int k=0;k<64;k++){ s1 = fmaf(Wri[j*64+k], Wv[k*64+c], s1); s2 = fmaf(Wrc[j*64+k], Wv[k*64+c], s2); }
    WriE[idx]=s1; WrcE[idx]=s2;
  }
  if (idx < 16){
    float s1=bri[idx], s2=brc[idx];
    for (int k=0;k<64;k++){ s1 = fmaf(Wri[idx*64+k], bv[k], s1); s2 = fmaf(Wrc[idx*64+k], bv[k], s2); }
    briE[idx]=s1; brcE[idx]=s2;
  }
}

// ---------- prep: transposed weight blobs ----------
__global__ void k_prep(const float* __restrict__ Wq, const float* __restrict__ Wk,
                       const float* __restrict__ Wo, const float* __restrict__ Wv,
                       const float* __restrict__ WriE, const float* __restrict__ WrcE,
                       float* __restrict__ WqT, float* __restrict__ WkT,
                       float* __restrict__ WoT, float* __restrict__ WT){
  int idx = blockIdx.x*256 + threadIdx.x;
  if (idx < 4096){
    int oc = idx>>6, c = idx&63;
    WqT[(c<<6)|oc] = Wq[idx];
    WkT[(c<<6)|oc] = Wk[idx];
    WoT[(c<<6)|oc] = Wo[idx];
    WT[c*96 + oc] = Wv[idx];
  } else if (idx < 6144){
    int t = idx - 4096;
    int j = (t>>6) & 15, c = t & 63;
    if (t < 1024) WT[c*96 + 64 + j] = WriE[j*64+c];
    else          WT[c*96 + 80 + j] = WrcE[j*64+c];
  }
}

// ---------- premask 1 ----------
__global__ void k_premask1(const float* __restrict__ Wm1, const float* __restrict__ bm1,
                           float* __restrict__ mrow1, float* __restrict__ mrow0){
  __shared__ float red[256];
  int j = blockIdx.x, tid = threadIdx.x;
  const float* row = Wm1 + (size_t)j*4096;
  float s=0.f;
  for (int e=tid;e<4096;e+=256) s += row[e];
  red[tid]=s; __syncthreads();
  for (int o=128;o;o>>=1){ if (tid<o) red[tid]+=red[tid+o]; __syncthreads(); }
  if (tid==0){
    float t = red[0]+bm1[j];
    mrow1[j] = lrelu(t);
    mrow0[j] = lrelu(bm1[j]);
  }
}

// ---------- premask 2 ----------
__global__ void k_premask2(const float* __restrict__ Wm2, const float* __restrict__ bm2,
                           const float* __restrict__ mrow1, const float* __restrict__ mrow0,
                           float* __restrict__ mask1, float* __restrict__ mask0){
  __shared__ float r1[256], r0[256];
  int e = blockIdx.x, tid = threadIdx.x;
  const float* row = Wm2 + (size_t)e*2048;
  float s1=0.f, s0=0.f;
  for (int j=tid;j<2048;j+=256){ float wv=row[j]; s1 = fmaf(wv, mrow1[j], s1); s0 = fmaf(wv, mrow0[j], s0); }
  r1[tid]=s1; r0[tid]=s0; __syncthreads();
  for (int o=128;o;o>>=1){ if (tid<o){ r1[tid]+=r1[tid+o]; r0[tid]+=r0[tid+o]; } __syncthreads(); }
  if (tid==0){ mask1[e]=r1[0]+bm2[e]; mask0[e]=r0[0]+bm2[e]; }
}

// ---------- K1: per-pixel v, xm, x_, block channel-sums ----------
__global__ __launch_bounds__(256) void k1_pw(
    const float* __restrict__ x, const float* __restrict__ WT,
    const float* __restrict__ bv,
    const float* __restrict__ briE, const float* __restrict__ brcE,
    const float* __restrict__ ln_w, const float* __restrict__ ln_b,
    float* __restrict__ v, float* __restrict__ x_, float* __restrict__ xm,
    float* __restrict__ bsum){
  __shared__ float wred[4][16];
  int tid = threadIdx.x;
  int b = blockIdx.x >> 8;
  int hw = ((blockIdx.x & 255) << 8) | tid;
  const float* xb = x + (((size_t)b)<<22) + hw;
  float acc[64], r1[16], rc[16];
  #pragma unroll
  for (int oc=0;oc<64;oc++) acc[oc]=0.f;
  #pragma unroll
  for (int j=0;j<16;j++){ r1[j]=0.f; rc[j]=0.f; }
  for (int c=0;c<64;c++){
    float xv = xb[((size_t)c)<<16];
    const float* wrow = WT + c*96;
    #pragma unroll
    for (int oc=0;oc<64;oc++) acc[oc] = fmaf(wrow[oc], xv, acc[oc]);
    #pragma unroll
    for (int j=0;j<16;j++){ r1[j] = fmaf(wrow[64+j], xv, r1[j]); rc[j] = fmaf(wrow[80+j], xv, rc[j]); }
  }
  float* vb = v + (((size_t)b)<<22) + hw;
  #pragma unroll
  for (int oc=0;oc<64;oc++) vb[((size_t)oc)<<16] = acc[oc] + bv[oc];
  float s1=0.f;
  #pragma unroll
  for (int j=0;j<16;j++){ float t = r1[j]+briE[j]; s1 += lrelu(t); }
  xm[(((size_t)b)<<16)+hw] = s1*(1.f/16.f);
  float u=0.f;
  #pragma unroll
  for (int j=0;j<16;j++){ rc[j] += brcE[j]; u += rc[j]; }
  u *= (1.f/16.f);
  float s2=0.f;
  #pragma unroll
  for (int j=0;j<16;j++){ float d = rc[j]-u; s2 += d*d; }
  float inv = 1.0f / sqrtf(s2*(1.f/16.f) + 1e-6f);
  float xs[16];
  #pragma unroll
  for (int j=0;j<16;j++){
    float t = (rc[j]-u)*inv*ln_w[j] + ln_b[j];
    t = lrelu(t);
    xs[j]=t;
    x_[(((size_t)(b*16+j))<<16)+hw] = t;
  }
  int lane = tid & 63, wv_ = tid >> 6;
  #pragma unroll
  for (int j=0;j<16;j++){
    float val = xs[j];
    for (int o=32;o;o>>=1) val += __shfl_down(val, o, 64);
    if (lane==0) wred[wv_][j]=val;
  }
  __syncthreads();
  if (tid<16) bsum[blockIdx.x*16+tid] = wred[0][tid]+wred[1][tid]+wred[2][tid]+wred[3][tid];
}

// ---------- K2: sa ----------
__global__ __launch_bounds__(256) void k2_sa(const float* __restrict__ x_,
    const float* __restrict__ Wsa, const float* __restrict__ bsa, float* __restrict__ sa){
  int idx = blockIdx.x*256 + threadIdx.x;
  int b = idx>>16; int hw = idx & 65535; int h = hw>>8, wcol = hw & 255;
  float acc = bsa[0];
  for (int ch=0; ch<16; ++ch){
    const float* plane = x_ + (((size_t)(b*16+ch))<<16);
    #pragma unroll
    for (int ky=0;ky<3;ky++){
      int y = h + ky - 1;
      if ((unsigned)y >= 256u) continue;
      #pragma unroll
      for (int kx=0;kx<3;kx++){
        int xx = wcol + kx - 1;
        if ((unsigned)xx >= 256u) continue;
        acc = fmaf(Wsa[ch*9+ky*3+kx], plane[(y<<8)+xx], acc);
      }
    }
  }
  sa[idx] = sigmoidf(acc);
}

// ---------- K3: ca ----------
__global__ void k3_ca(const float* __restrict__ bsum, const float* __restrict__ Wca,
                      const float* __restrict__ bca, float* __restrict__ ca){
  __shared__ float meanx[4][16];
  int tid = threadIdx.x;
  if (tid < 64){
    int b = tid>>4, j = tid&15;
    float s=0.f;
    for (int blk=0;blk<256;blk++) s += bsum[(b*256+blk)*16 + j];
    meanx[b][j] = s*(1.f/65536.f);
  }
  __syncthreads();
  int b = tid>>6, oc = tid&63;
  float a = bca[oc];
  #pragma unroll
  for (int j=0;j<16;j++) a = fmaf(Wca[oc*16+j], meanx[b][j], a);
  ca[tid] = sigmoidf(a);
}

// ---------- K4a: per-window variance ----------
__global__ void k4a_var(const float* __restrict__ xm, float* __restrict__ var){
  int t = blockIdx.x*256 + threadIdx.x;
  int b = t>>10, n = t&1023, wh = n>>5, ww = n&31;
  const float* base = xm + (((size_t)b)<<16) + (wh<<11) + (ww<<3);
  float s=0.f;
  #pragma unroll
  for (int dh=0;dh<8;dh++){
    #pragma unroll
    for (int dw=0;dw<8;dw++) s += base[(dh<<8)+dw];
  }
  float mean = s*(1.f/64.f);
  float ss=0.f;
  #pragma unroll
  for (int dh=0;dh<8;dh++){
    #pragma unroll
    for (int dw=0;dw<8;dw++){ float d = base[(dh<<8)+dw]-mean; ss += d*d; }
  }
  var[t] = ss*(1.f/63.f);
}

// ---------- K4b: rank -> sel ----------
__global__ __launch_bounds__(1024) void k4b_sel(const float* __restrict__ var, float* __restrict__ sel){
  __shared__ float vs[1024];
  int b = blockIdx.x, tid = threadIdx.x;
  float mine = var[b*1024+tid];
  vs[tid]=mine; __syncthreads();
  int rank=0;
  for (int j=0;j<1024;j++){
    float o = vs[j];
    rank += (o < mine) || (o == mine && j < tid);
  }
  sel[b*1024+tid] = (rank >= 512) ? 1.f : 0.f;
}

// ---------- K6: per-window attention, register-blocked fp32 GEMMs ----------
// Thread (lane, wv): row=lane for all GEMMs, 16-col slice j0=wv*16.
// LDS tiles 16B-block XOR-swizzled: word(r,c) = (r<<6)|(((c>>2)^(r&15))<<2)|(c&3)
__global__ __launch_bounds__(256) void k6_attn(
    const float* __restrict__ x, const float* __restrict__ v, const float* __restrict__ sa,
    const float* __restrict__ sel,
    const float* __restrict__ mask1, const float* __restrict__ mask0,
    const float* __restrict__ WqT, const float* __restrict__ WkT,
    const float* __restrict__ bq, const float* __restrict__ bk,
    float* __restrict__ out){
  __shared__ __align__(16) float VM[4096];
  __shared__ __align__(16) float QS[4096];
  __shared__ __align__(16) float KS[4096];
  __shared__ float saw[64];
  __shared__ float scr[512];
  int tid = threadIdx.x;
  int lane = tid & 63, wv = tid >> 6;
  int j0 = wv << 4;
  int j0u = __builtin_amdgcn_readfirstlane(j0);
  int wg = ((blockIdx.x & 7) << 9) | (blockIdx.x >> 3);
  int b = wg >> 10, n = wg & 1023, wh = n >> 5, ww = n & 31;
  const float* mv = (sel[wg] > 0.5f) ? mask1 : mask0;
  size_t xbase = ((size_t)b) << 22;
  int pix0 = (wh << 11) | (ww << 3);
  int gofs = ((lane>>3)<<8) | (lane&7);
  size_t gpix = xbase + pix0 + gofs;
  const float* mrow = mv + (lane<<6);

  float xm[64];
  #pragma unroll
  for (int cb=0;cb<16;cb++){
    float4 m4 = *(const float4*)&mrow[cb*4];
    xm[4*cb+0] = x[gpix + ((size_t)(4*cb+0)<<16)] * m4.x;
    xm[4*cb+1] = x[gpix + ((size_t)(4*cb+1)<<16)] * m4.y;
    xm[4*cb+2] = x[gpix + ((size_t)(4*cb+2)<<16)] * m4.z;
    xm[4*cb+3] = x[gpix + ((size_t)(4*cb+3)<<16)] * m4.w;
  }
  #pragma unroll
  for (int g=0; g<4; ++g){
    int cb = (j0>>2) + g;
    float4 m4 = *(const float4*)&mrow[cb*4];
    float4 vm4;
    vm4.x = v[gpix + ((size_t)(4*cb+0)<<16)] * m4.x;
    vm4.y = v[gpix + ((size_t)(4*cb+1)<<16)] * m4.y;
    vm4.z = v[gpix + ((size_t)(4*cb+2)<<16)] * m4.z;
    vm4.w = v[gpix + ((size_t)(4*cb+3)<<16)] * m4.w;
    int wb = (lane<<6) | ((cb ^ (lane&15))<<2);
    *(float4*)&VM[wb] = vm4;
  }
  if (tid < 64) saw[tid] = sa[(((size_t)b)<<16) + pix0 + ((tid>>3)<<8) + (tid&7)];
  __syncthreads();

  float q[16], k[16];
  #pragma unroll
  for (int jj=0;jj<16;jj++){ q[jj]=bq[j0u+jj]; k[jj]=bk[j0u+jj]; }
  #pragma unroll
  for (int c=0;c<64;c++){
    float av = xm[c];
    const float* wqr = WqT + (c<<6) + j0u;
    const float* wkr = WkT + (c<<6) + j0u;
    #pragma unroll
    for (int jj=0;jj<16;jj++){
      q[jj] = fmaf(av, wqr[jj], q[jj]);
      k[jj] = fmaf(av, wkr[jj], k[jj]);
    }
  }
  #pragma unroll
  for (int g=0; g<4; ++g){
    int cb = (j0>>2)+g;
    int wb = (lane<<6) | ((cb ^ (lane&15))<<2);
    *(float4*)&QS[wb] = make_float4(q[4*g],q[4*g+1],q[4*g+2],q[4*g+3]);
    *(float4*)&KS[wb] = make_float4(k[4*g],k[4*g+1],k[4*g+2],k[4*g+3]);
  }
  __syncthreads();

  float s[16];
  #pragma unroll
  for (int jj=0;jj<16;jj++) s[jj]=0.f;
  #pragma unroll
  for (int ob=0; ob<16; ++ob){
    int wbA = (lane<<6) | ((ob ^ (lane&15))<<2);
    float4 a = *(const float4*)&QS[wbA];
    #pragma unroll
    for (int jj=0;jj<16;jj++){
      int j = j0+jj;
      int wbB = (j<<6) | ((ob ^ (j&15))<<2);
      float4 bb = *(const float4*)&KS[wbB];
      s[jj] = fmaf(a.x, bb.x, s[jj]);
      s[jj] = fmaf(a.y, bb.y, s[jj]);
      s[jj] = fmaf(a.z, bb.z, s[jj]);
      s[jj] = fmaf(a.w, bb.w, s[jj]);
    }
  }
  float pmax = s[0];
  #pragma unroll
  for (int jj=1;jj<16;jj++) pmax = fmaxf(pmax, s[jj]);
  scr[(wv<<6)+lane] = pmax;
  __syncthreads();
  float rmax = fmaxf(fmaxf(scr[lane], scr[64+lane]), fmaxf(scr[128+lane], scr[192+lane]));
  float psum = 0.f;
  #pragma unroll
  for (int jj=0;jj<16;jj++){ s[jj] = expf(s[jj]-rmax); psum += s[jj]; }
  scr[256+(wv<<6)+lane] = psum;
  __syncthreads();
  float rsum = scr[256+lane]+scr[320+lane]+scr[384+lane]+scr[448+lane];
  float inv = 1.f/rsum;
  #pragma unroll
  for (int g=0; g<4; ++g){
    int cb = (j0>>2)+g;
    int wb = (lane<<6) | ((cb ^ (lane&15))<<2);
    *(float4*)&QS[wb] = make_float4(s[4*g]*inv, s[4*g+1]*inv, s[4*g+2]*inv, s[4*g+3]*inv);
  }
  __syncthreads();

  float f[16];
  #pragma unroll
  for (int jj=0;jj<16;jj++) f[jj]=0.f;
  #pragma unroll
  for (int jb=0;jb<16;++jb){
    int wbA = (lane<<6) | ((jb ^ (lane&15))<<2);
    float4 a = *(const float4*)&QS[wbA];
    #pragma unroll
    for (int t=0;t<4;t++){
      int j = 4*jb+t;
      float av = (t==0)?a.x:(t==1)?a.y:(t==2)?a.z:a.w;
      #pragma unroll
      for (int g=0; g<4; ++g){
        int cb = (j0>>2)+g;
        int wbB = (j<<6) | ((cb ^ (j&15))<<2);
        float4 bb = *(const float4*)&VM[wbB];
        f[4*g+0] = fmaf(av, bb.x, f[4*g+0]);
        f[4*g+1] = fmaf(av, bb.y, f[4*g+1]);
        f[4*g+2] = fmaf(av, bb.z, f[4*g+2]);
        f[4*g+3] = fmaf(av, bb.w, f[4*g+3]);
      }
    }
  }
  float sav = saw[lane];
  #pragma unroll
  for (int g=0; g<4; ++g){
    int cb = (j0>>2)+g;
    int wb = (lane<<6) | ((cb ^ (lane&15))<<2);
    float4 vmv = *(const float4*)&VM[wb];
    #pragma unroll
    for (int t=0;t<4;t++){
      int c = 4*cb+t;
      size_t gaddr = xbase + ((size_t)c<<16) + pix0 + gofs;
      float vv = v[gaddr];
      float vmx = (t==0)?vmv.x:(t==1)?vmv.y:(t==2)?vmv.z:vmv.w;
      out[gaddr] = f[4*g+t] + sav*(vv - vmx);
    }
  }
}

// ---------- K7: fused dw3x3(pad1) -> dw3x3(dil2,pad2) -> gelu*ca + residual ----------
// Reads `in` (attn output), writes `dwout` (separate buffer -> no halo race).
// C1 forced to 0 outside the image (conv2's zero padding semantics).
__global__ __launch_bounds__(256) void k7_fused(const float* __restrict__ in,
    const float* __restrict__ Wd1, const float* __restrict__ bd1,
    const float* __restrict__ Wd2, const float* __restrict__ bd2,
    const float* __restrict__ ca, float* __restrict__ dwout){
  __shared__ float IN[22*23];
  __shared__ float C1[20*21];
  int blk = blockIdx.x;
  int tx = blk & 15, ty = (blk>>4) & 15, ch = (blk>>8) & 63, b = blk>>14;
  int x0 = tx<<4, y0 = ty<<4;
  const float* plane = in + (((size_t)(b*64+ch))<<16);
  int tid = threadIdx.x;
  for (int e = tid; e < 484; e += 256){
    int r = e/22, cc = e - r*22;
    int y = y0 + r - 3, xx = x0 + cc - 3;
    float vv = 0.f;
    if ((unsigned)y < 256u && (unsigned)xx < 256u) vv = plane[(y<<8)+xx];
    IN[r*23+cc] = vv;
  }
  __syncthreads();
  float w1[9], w2[9];
  #pragma unroll
  for (int t=0;t<9;t++){ w1[t]=Wd1[ch*9+t]; w2[t]=Wd2[ch*9+t]; }
  float b1 = bd1[ch];
  for (int e = tid; e < 400; e += 256){
    int r = e/20, cc = e - r*20;
    int yc1 = y0 + r - 2, xc1 = x0 + cc - 2;
    float acc = 0.f;
    if ((unsigned)yc1 < 256u && (unsigned)xc1 < 256u){
      acc = b1;
      #pragma unroll
      for (int ky=0;ky<3;ky++)
        #pragma unroll
        for (int kx=0;kx<3;kx++)
          acc = fmaf(w1[ky*3+kx], IN[(r+ky)*23 + cc+kx], acc);
    }
    C1[r*21+cc] = acc;
  }
  __syncthreads();
  int px = tid & 15, py = tid >> 4;
  float acc = bd2[ch];
  #pragma unroll
  for (int ky=0;ky<3;ky++)
    #pragma unroll
    for (int kx=0;kx<3;kx++)
      acc = fmaf(w2[ky*3+kx], C1[(py+2*ky)*21 + px+2*kx], acc);
  float g = 0.5f*acc*(1.f + erff(acc*0.70710678118654752f));
  float resid = IN[(py+3)*23 + px+3];
  size_t o = (((size_t)(b*64+ch))<<16) + ((size_t)((y0+py)<<8)) + x0+px;
  dwout[o] = fmaf(g, ca[b*64+ch], resid);
}

// ---------- K7c: final 1x1 conv ----------
__global__ __launch_bounds__(256) void k7c_proj(const float* __restrict__ in,
    const float* __restrict__ WoT, const float* __restrict__ bo, float* __restrict__ out){
  int b = blockIdx.x >> 8;
  int hw = ((blockIdx.x & 255) << 8) | threadIdx.x;
  const float* pb = in + (((size_t)b)<<22) + hw;
  float acc[64];
  #pragma unroll
  for (int oc=0;oc<64;oc++) acc[oc]=bo[oc];
  for (int c=0;c<64;c++){
    float xv = pb[((size_t)c)<<16];
    const float* wrow = WoT + (c<<6);
    #pragma unroll
    for (int oc=0;oc<64;oc++) acc[oc] = fmaf(wrow[oc], xv, acc[oc]);
  }
  float* ob = out + (((size_t)b)<<22) + hw;
  #pragma unroll
  for (int oc=0;oc<64;oc++) ob[((size_t)oc)<<16] = acc[oc];
}

extern "C" void kernel_launch(void* const* d_in, const int* in_sizes, int n_in,
                              void* d_out, int out_size, void* d_ws, size_t ws_size,
                              hipStream_t stream) {
  const float* x    = (const float*)d_in[0];
  const float* Wv   = (const float*)d_in[1];
  const float* bv   = (const float*)d_in[2];
  const float* Wri  = (const float*)d_in[3];
  const float* bri  = (const float*)d_in[4];
  const float* Wrc  = (const float*)d_in[5];
  const float* brc  = (const float*)d_in[6];
  const float* ln_w = (const float*)d_in[7];
  const float* ln_b = (const float*)d_in[8];
  const float* Wca  = (const float*)d_in[9];
  const float* bca  = (const float*)d_in[10];
  const float* Wsa  = (const float*)d_in[11];
  const float* bsa  = (const float*)d_in[12];
  const float* Wm1  = (const float*)d_in[13];
  const float* bm1  = (const float*)d_in[14];
  const float* Wm2  = (const float*)d_in[15];
  const float* bm2  = (const float*)d_in[16];
  const float* Wq   = (const float*)d_in[17];
  const float* bq   = (const float*)d_in[18];
  const float* Wk   = (const float*)d_in[19];
  const float* bk   = (const float*)d_in[20];
  const float* Wd1  = (const float*)d_in[21];
  const float* bd1  = (const float*)d_in[22];
  const float* Wd2  = (const float*)d_in[23];
  const float* bd2  = (const float*)d_in[24];
  const float* Wo   = (const float*)d_in[25];
  const float* bo   = (const float*)d_in[26];
  float* out = (float*)d_out;

  float* ws = (float*)d_ws;
  float* v_buf   = ws;                    // 16777216
  float* out_buf = v_buf + 16777216;      // 16777216
  float* x_buf   = out_buf + 16777216;    // 4194304
  float* xm_buf  = x_buf + 4194304;       // 262144
  float* sa_buf  = xm_buf + 262144;       // 262144
  float* bsum    = sa_buf + 262144;       // 16384
  float* ca_buf  = bsum + 16384;          // 256
  float* var_buf = ca_buf + 256;          // 4096
  float* sel_buf = var_buf + 4096;        // 4096
  float* mrow1   = sel_buf + 4096;        // 2048
  float* mrow0   = mrow1 + 2048;          // 2048
  float* mask1   = mrow0 + 2048;          // 4096
  float* mask0   = mask1 + 4096;          // 4096
  float* WqT     = mask0 + 4096;          // 4096
  float* WkT     = WqT + 4096;            // 4096
  float* WoT     = WkT + 4096;            // 4096
  float* WT      = WoT + 4096;            // 6144
  float* WriE    = WT + 6144;             // 1024
  float* WrcE    = WriE + 1024;           // 1024
  float* briE    = WrcE + 1024;           // 16
  float* brcE    = briE + 16;             // 16
  float* dw_buf  = v_buf;                 // reuse: v dead after k6

  k0_combine<<<4,256,0,stream>>>(Wv,bv,Wri,bri,Wrc,brc,WriE,briE,WrcE,brcE);
  k_prep<<<24,256,0,stream>>>(Wq,Wk,Wo,Wv,WriE,WrcE,WqT,WkT,WoT,WT);
  k_premask1<<<2048,256,0,stream>>>(Wm1,bm1,mrow1,mrow0);
  k_premask2<<<4096,256,0,stream>>>(Wm2,bm2,mrow1,mrow0,mask1,mask0);
  k1_pw<<<1024,256,0,stream>>>(x,WT,bv,briE,brcE,ln_w,ln_b,v_buf,x_buf,xm_buf,bsum);
  k2_sa<<<1024,256,0,stream>>>(x_buf,Wsa,bsa,sa_buf);
  k3_ca<<<1,256,0,stream>>>(bsum,Wca,bca,ca_buf);
  k4a_var<<<16,256,0,stream>>>(xm_buf,var_buf);
  k4b_sel<<<4,1024,0,stream>>>(var_buf,sel_buf);
  k6_attn<<<4096,256,0,stream>>>(x,v_buf,sa_buf,sel_buf,mask1,mask0,WqT,WkT,bq,bk,out_buf);
  k7_fused<<<65536,256,0,stream>>>(out_buf,Wd1,bd1,Wd2,bd2,ca_buf,dw_buf);
  k7c_proj<<<1024,256,0,stream>>>(dw_buf,WoT,bo,out);
}

// Round 5
// 393.510 us; speedup vs baseline: 2.1505x; 1.5103x over previous
//
#include <hip/hip_runtime.h>
#include <hip/hip_bf16.h>
#include <math.h>

typedef __attribute__((ext_vector_type(8))) short short8;
typedef __attribute__((ext_vector_type(16))) float f32x16;

__device__ __forceinline__ float lrelu(float x){ return x >= 0.f ? x : 0.1f*x; }
__device__ __forceinline__ float sigmoidf(float x){ return 1.f/(1.f+expf(-x)); }
__device__ __forceinline__ short f2bf(float f){
  __hip_bfloat16 hb = __float2bfloat16(f);
  return *reinterpret_cast<short*>(&hb);
}
__device__ __forceinline__ float bf16f(short s){
  return __uint_as_float(((unsigned)(unsigned short)s)<<16);
}

// ---------- K0: effective weights WriE = Wri@Wv, WrcE = Wrc@Wv, biases ----------
__global__ void k0_combine(const float* __restrict__ Wv, const float* __restrict__ bv,
                           const float* __restrict__ Wri, const float* __restrict__ bri,
                           const float* __restrict__ Wrc, const float* __restrict__ brc,
                           float* __restrict__ WriE, float* __restrict__ briE,
                           float* __restrict__ WrcE, float* __restrict__ brcE){
  int idx = blockIdx.x*256 + threadIdx.x;
  if (idx < 1024){
    int j = idx>>6, c = idx&63;
    float s1=0.f, s2=0.f;
    for (int k=0;k<64;k++){ s1 = fmaf(Wri[j*64+k], Wv[k*64+c], s1); s2 = fmaf(Wrc[j*64+k], Wv[k*64+c], s2); }
    WriE[idx]=s1; WrcE[idx]=s2;
  }
  if (idx < 16){
    float s1=bri[idx], s2=brc[idx];
    for (int k=0;k<64;k++){ s1 = fmaf(Wri[idx*64+k], bv[k], s1); s2 = fmaf(Wrc[idx*64+k], bv[k], s2); }
    briE[idx]=s1; brcE[idx]=s2;
  }
}

// ---------- prep: WT/WoT blobs + MFMA W-frag blob (hi/lo, bias column kt=4) ----------
// WFrag layout: (((w*2+part)*2+mt)*5+kt)*512 + lane*8 + i  (shorts)
__global__ void k_prep(const float* __restrict__ Wq, const float* __restrict__ Wk,
                       const float* __restrict__ Wo, const float* __restrict__ Wv,
                       const float* __restrict__ WriE, const float* __restrict__ WrcE,
                       const float* __restrict__ bq, const float* __restrict__ bk,
                       float* __restrict__ WoT, float* __restrict__ WT,
                       short* __restrict__ WFrag){
  int idx = blockIdx.x*256 + threadIdx.x;
  if (idx < 4096){
    int oc = idx>>6, c = idx&63;
    WoT[(c<<6)|oc] = Wo[idx];
    WT[c*96 + oc] = Wv[idx];
  } else if (idx < 6144){
    int t = idx - 4096;
    int j = (t>>6) & 15, c = t & 63;
    if (t < 1024) WT[c*96 + 64 + j] = WriE[j*64+c];
    else          WT[c*96 + 80 + j] = WrcE[j*64+c];
  }
  if (idx < 2560){
    int w = idx / 1280;
    int r1 = idx - w*1280;
    int part = r1 / 640;
    int r2 = r1 - part*640;
    int mt = r2 / 320;
    int r3 = r2 - mt*320;
    int kt = r3 >> 6;
    int lane = r3 & 63;
    const float* W = w ? Wk : Wq;
    const float* B = w ? bk : bq;
    int j = (mt<<5) | (lane & 31);
    int hh = lane >> 5;
    short8 frag;
    #pragma unroll
    for (int i=0;i<8;i++){
      int kl = (hh<<2) + (i&3) + ((i>>2)<<3);
      float val;
      if (kt < 4) val = W[j*64 + (kt<<4) + kl];
      else        val = (kl==0) ? B[j] : 0.f;
      short hi = f2bf(val);
      frag[i] = part ? f2bf(val - bf16f(hi)) : hi;
    }
    *(short8*)&WFrag[idx<<3] = frag;
  }
}

// ---------- premask 1 ----------
__global__ void k_premask1(const float* __restrict__ Wm1, const float* __restrict__ bm1,
                           float* __restrict__ mrow1, float* __restrict__ mrow0){
  __shared__ float red[256];
  int j = blockIdx.x, tid = threadIdx.x;
  const float* row = Wm1 + (size_t)j*4096;
  float s=0.f;
  for (int e=tid;e<4096;e+=256) s += row[e];
  red[tid]=s; __syncthreads();
  for (int o=128;o;o>>=1){ if (tid<o) red[tid]+=red[tid+o]; __syncthreads(); }
  if (tid==0){
    float t = red[0]+bm1[j];
    mrow1[j] = lrelu(t);
    mrow0[j] = lrelu(bm1[j]);
  }
}

// ---------- premask 2 (+ transposed copies) ----------
__global__ void k_premask2(const float* __restrict__ Wm2, const float* __restrict__ bm2,
                           const float* __restrict__ mrow1, const float* __restrict__ mrow0,
                           float* __restrict__ mask1, float* __restrict__ mask0,
                           float* __restrict__ mask1T, float* __restrict__ mask0T){
  __shared__ float r1[256], r0[256];
  int e = blockIdx.x, tid = threadIdx.x;
  const float* row = Wm2 + (size_t)e*2048;
  float s1=0.f, s0=0.f;
  for (int j=tid;j<2048;j+=256){ float wv=row[j]; s1 = fmaf(wv, mrow1[j], s1); s0 = fmaf(wv, mrow0[j], s0); }
  r1[tid]=s1; r0[tid]=s0; __syncthreads();
  for (int o=128;o;o>>=1){ if (tid<o){ r1[tid]+=r1[tid+o]; r0[tid]+=r0[tid+o]; } __syncthreads(); }
  if (tid==0){
    float m1 = r1[0]+bm2[e], m0 = r0[0]+bm2[e];
    mask1[e]=m1; mask0[e]=m0;
    int p = e>>6, c = e&63;
    mask1T[(c<<6)|p]=m1; mask0T[(c<<6)|p]=m0;
  }
}

// ---------- K1: per-pixel v, xm, x_, block channel-sums ----------
__global__ __launch_bounds__(256) void k1_pw(
    const float* __restrict__ x, const float* __restrict__ WT,
    const float* __restrict__ bv,
    const float* __restrict__ briE, const float* __restrict__ brcE,
    const float* __restrict__ ln_w, const float* __restrict__ ln_b,
    float* __restrict__ v, float* __restrict__ x_, float* __restrict__ xm,
    float* __restrict__ bsum){
  __shared__ float wred[4][16];
  int tid = threadIdx.x;
  int b = blockIdx.x >> 8;
  int hw = ((blockIdx.x & 255) << 8) | tid;
  const float* xb = x + (((size_t)b)<<22) + hw;
  float acc[64], r1[16], rc[16];
  #pragma unroll
  for (int oc=0;oc<64;oc++) acc[oc]=0.f;
  #pragma unroll
  for (int j=0;j<16;j++){ r1[j]=0.f; rc[j]=0.f; }
  for (int c=0;c<64;c++){
    float xv = xb[((size_t)c)<<16];
    const float* wrow = WT + c*96;
    #pragma unroll
    for (int oc=0;oc<64;oc++) acc[oc] = fmaf(wrow[oc], xv, acc[oc]);
    #pragma unroll
    for (int j=0;j<16;j++){ r1[j] = fmaf(wrow[64+j], xv, r1[j]); rc[j] = fmaf(wrow[80+j], xv, rc[j]); }
  }
  float* vb = v + (((size_t)b)<<22) + hw;
  #pragma unroll
  for (int oc=0;oc<64;oc++) vb[((size_t)oc)<<16] = acc[oc] + bv[oc];
  float s1=0.f;
  #pragma unroll
  for (int j=0;j<16;j++){ float t = r1[j]+briE[j]; s1 += lrelu(t); }
  xm[(((size_t)b)<<16)+hw] = s1*(1.f/16.f);
  float u=0.f;
  #pragma unroll
  for (int j=0;j<16;j++){ rc[j] += brcE[j]; u += rc[j]; }
  u *= (1.f/16.f);
  float s2=0.f;
  #pragma unroll
  for (int j=0;j<16;j++){ float d = rc[j]-u; s2 += d*d; }
  float inv = 1.0f / sqrtf(s2*(1.f/16.f) + 1e-6f);
  float xs[16];
  #pragma unroll
  for (int j=0;j<16;j++){
    float t = (rc[j]-u)*inv*ln_w[j] + ln_b[j];
    t = lrelu(t);
    xs[j]=t;
    x_[(((size_t)(b*16+j))<<16)+hw] = t;
  }
  int lane = tid & 63, wv_ = tid >> 6;
  #pragma unroll
  for (int j=0;j<16;j++){
    float val = xs[j];
    for (int o=32;o;o>>=1) val += __shfl_down(val, o, 64);
    if (lane==0) wred[wv_][j]=val;
  }
  __syncthreads();
  if (tid<16) bsum[blockIdx.x*16+tid] = wred[0][tid]+wred[1][tid]+wred[2][tid]+wred[3][tid];
}

// ---------- K2: sa ----------
__global__ __launch_bounds__(256) void k2_sa(const float* __restrict__ x_,
    const float* __restrict__ Wsa, const float* __restrict__ bsa, float* __restrict__ sa){
  int idx = blockIdx.x*256 + threadIdx.x;
  int b = idx>>16; int hw = idx & 65535; int h = hw>>8, wcol = hw & 255;
  float acc = bsa[0];
  for (int ch=0; ch<16; ++ch){
    const float* plane = x_ + (((size_t)(b*16+ch))<<16);
    #pragma unroll
    for (int ky=0;ky<3;ky++){
      int y = h + ky - 1;
      if ((unsigned)y >= 256u) continue;
      #pragma unroll
      for (int kx=0;kx<3;kx++){
        int xx = wcol + kx - 1;
        if ((unsigned)xx >= 256u) continue;
        acc = fmaf(Wsa[ch*9+ky*3+kx], plane[(y<<8)+xx], acc);
      }
    }
  }
  sa[idx] = sigmoidf(acc);
}

// ---------- K3: ca ----------
__global__ void k3_ca(const float* __restrict__ bsum, const float* __restrict__ Wca,
                      const float* __restrict__ bca, float* __restrict__ ca){
  __shared__ float meanx[4][16];
  int tid = threadIdx.x;
  if (tid < 64){
    int b = tid>>4, j = tid&15;
    float s=0.f;
    for (int blk=0;blk<256;blk++) s += bsum[(b*256+blk)*16 + j];
    meanx[b][j] = s*(1.f/65536.f);
  }
  __syncthreads();
  int b = tid>>6, oc = tid&63;
  float a = bca[oc];
  #pragma unroll
  for (int j=0;j<16;j++) a = fmaf(Wca[oc*16+j], meanx[b][j], a);
  ca[tid] = sigmoidf(a);
}

// ---------- K4a: per-window variance ----------
__global__ void k4a_var(const float* __restrict__ xm, float* __restrict__ var){
  int t = blockIdx.x*256 + threadIdx.x;
  int b = t>>10, n = t&1023, wh = n>>5, ww = n&31;
  const float* base = xm + (((size_t)b)<<16) + (wh<<11) + (ww<<3);
  float s=0.f;
  #pragma unroll
  for (int dh=0;dh<8;dh++){
    #pragma unroll
    for (int dw=0;dw<8;dw++) s += base[(dh<<8)+dw];
  }
  float mean = s*(1.f/64.f);
  float ss=0.f;
  #pragma unroll
  for (int dh=0;dh<8;dh++){
    #pragma unroll
    for (int dw=0;dw<8;dw++){ float d = base[(dh<<8)+dw]-mean; ss += d*d; }
  }
  var[t] = ss*(1.f/63.f);
}

// ---------- K4b: rank -> sel ----------
__global__ __launch_bounds__(1024) void k4b_sel(const float* __restrict__ var, float* __restrict__ sel){
  __shared__ float vs[1024];
  int b = blockIdx.x, tid = threadIdx.x;
  float mine = var[b*1024+tid];
  vs[tid]=mine; __syncthreads();
  int rank=0;
  for (int j=0;j<1024;j++){
    float o = vs[j];
    rank += (o < mine) || (o == mine && j < tid);
  }
  sel[b*1024+tid] = (rank >= 512) ? 1.f : 0.f;
}

// ---------- K6: per-window attention via bf16 MFMA, hi/lo split precision ----------
// 1 wave = 1 window. C-tile->frag conversion is in-lane: frag[kk][i] = C[8*kk+i].
__global__ __launch_bounds__(256, 2) void k6_attn(
    const float* __restrict__ x, const float* __restrict__ v, const float* __restrict__ sa,
    const float* __restrict__ sel,
    const float* __restrict__ mask1, const float* __restrict__ mask0,
    const float* __restrict__ mask1T, const float* __restrict__ mask0T,
    const short* __restrict__ WFrag,
    float* __restrict__ out){
  __shared__ short8 QBlds[4][16][64];   // per-wave parked Q frags (hi 0-7, lo 8-15)
  int tid = threadIdx.x;
  int lane = tid & 63, wvi = tid >> 6;
  int l31 = lane & 31, h = lane >> 5;
  int bid = blockIdx.x;
  int blk = ((bid & 7) << 7) | (bid >> 3);      // 1024 = 8*128 bijective XCD swizzle
  int wg = (blk << 2) | wvi;
  int b = wg >> 10, n = wg & 1023;
  int pix0 = ((n >> 5) << 11) | ((n & 31) << 3);
  bool sel1 = sel[wg] > 0.5f;
  const float* mrow  = sel1 ? mask1  : mask0;
  const float* mrowT = sel1 ? mask1T : mask0T;
  size_t cbase = (((size_t)b) << 22) + pix0;

  // ---- Xm B-frags (hi/lo), lane = pixel ----
  short8 XBh[2][4], XBl[2][4];
  #pragma unroll
  for (int nt=0;nt<2;nt++){
    int p = (nt<<5) | l31;
    size_t gp = cbase + ((size_t)((p>>3)<<8)) + (p&7);
    const float* mr = mrow + (p<<6);
    #pragma unroll
    for (int kt=0;kt<4;kt++){
      float4 ma = *(const float4*)&mr[(kt<<4)+(h<<2)];
      float4 mb = *(const float4*)&mr[(kt<<4)+(h<<2)+8];
      float xv[8];
      #pragma unroll
      for (int i=0;i<8;i++){
        int c = (kt<<4) + (h<<2) + (i&3) + ((i>>2)<<3);
        xv[i] = x[gp + ((size_t)c<<16)];
      }
      xv[0]*=ma.x; xv[1]*=ma.y; xv[2]*=ma.z; xv[3]*=ma.w;
      xv[4]*=mb.x; xv[5]*=mb.y; xv[6]*=mb.z; xv[7]*=mb.w;
      short8 fh, fl;
      #pragma unroll
      for (int i=0;i<8;i++){
        short hi = f2bf(xv[i]); fh[i]=hi; fl[i]=f2bf(xv[i]-bf16f(hi));
      }
      XBh[nt][kt]=fh; XBl[nt][kt]=fl;
    }
  }
  short8 CB;
  #pragma unroll
  for (int i=0;i<8;i++) CB[i]=0;
  CB[0] = h ? (short)0 : (short)0x3F80;   // bf16(1.0) at k==0

  // ---- Q projection: Qt[mt_j][nt_p] = Wq @ Xm^T (+bias col), then park frags ----
  #pragma unroll
  for (int mt=0;mt<2;mt++){
    short8 WAh[5], WAl[5];
    #pragma unroll
    for (int kt=0;kt<5;kt++){
      WAh[kt] = *(const short8*)&WFrag[(((0*2+0)*2+mt)*5+kt)*512 + (lane<<3)];
      WAl[kt] = *(const short8*)&WFrag[(((0*2+1)*2+mt)*5+kt)*512 + (lane<<3)];
    }
    #pragma unroll
    for (int nt=0;nt<2;nt++){
      f32x16 acc;
      #pragma unroll
      for (int r=0;r<16;r++) acc[r]=0.f;
      #pragma unroll
      for (int kt=0;kt<4;kt++){
        acc = __builtin_amdgcn_mfma_f32_32x32x16_bf16(WAh[kt], XBh[nt][kt], acc, 0,0,0);
        acc = __builtin_amdgcn_mfma_f32_32x32x16_bf16(WAh[kt], XBl[nt][kt], acc, 0,0,0);
        acc = __builtin_amdgcn_mfma_f32_32x32x16_bf16(WAl[kt], XBh[nt][kt], acc, 0,0,0);
      }
      acc = __builtin_amdgcn_mfma_f32_32x32x16_bf16(WAh[4], CB, acc, 0,0,0);
      acc = __builtin_amdgcn_mfma_f32_32x32x16_bf16(WAl[4], CB, acc, 0,0,0);
      // convert C-tile -> B-frags (kt_j = 2mt+kk), hi/lo, park in LDS
      short8 fh0, fh1, fl0, fl1;
      #pragma unroll
      for (int i=0;i<8;i++){
        short hi0 = f2bf(acc[i]);   fh0[i]=hi0; fl0[i]=f2bf(acc[i]-bf16f(hi0));
        short hi1 = f2bf(acc[8+i]); fh1[i]=hi1; fl1[i]=f2bf(acc[8+i]-bf16f(hi1));
      }
      QBlds[wvi][(2*mt  )*2+nt][lane] = fh0;
      QBlds[wvi][(2*mt+1)*2+nt][lane] = fh1;
      QBlds[wvi][8+(2*mt  )*2+nt][lane] = fl0;
      QBlds[wvi][8+(2*mt+1)*2+nt][lane] = fl1;
    }
  }

  // ---- K projection -> KA A-frags [mt_pk][kt_j] (hi/lo) in regs ----
  short8 KAh[2][4], KAl[2][4];
  #pragma unroll
  for (int mt=0;mt<2;mt++){
    short8 WAh[5], WAl[5];
    #pragma unroll
    for (int kt=0;kt<5;kt++){
      WAh[kt] = *(const short8*)&WFrag[(((1*2+0)*2+mt)*5+kt)*512 + (lane<<3)];
      WAl[kt] = *(const short8*)&WFrag[(((1*2+1)*2+mt)*5+kt)*512 + (lane<<3)];
    }
    #pragma unroll
    for (int nt=0;nt<2;nt++){
      f32x16 acc;
      #pragma unroll
      for (int r=0;r<16;r++) acc[r]=0.f;
      #pragma unroll
      for (int kt=0;kt<4;kt++){
        acc = __builtin_amdgcn_mfma_f32_32x32x16_bf16(WAh[kt], XBh[nt][kt], acc, 0,0,0);
        acc = __builtin_amdgcn_mfma_f32_32x32x16_bf16(WAh[kt], XBl[nt][kt], acc, 0,0,0);
        acc = __builtin_amdgcn_mfma_f32_32x32x16_bf16(WAl[kt], XBh[nt][kt], acc, 0,0,0);
      }
      acc = __builtin_amdgcn_mfma_f32_32x32x16_bf16(WAh[4], CB, acc, 0,0,0);
      acc = __builtin_amdgcn_mfma_f32_32x32x16_bf16(WAl[4], CB, acc, 0,0,0);
      #pragma unroll
      for (int i=0;i<8;i++){
        short hi0 = f2bf(acc[i]);   KAh[nt][2*mt  ][i]=hi0; KAl[nt][2*mt  ][i]=f2bf(acc[i]-bf16f(hi0));
        short hi1 = f2bf(acc[8+i]); KAh[nt][2*mt+1][i]=hi1; KAl[nt][2*mt+1][i]=f2bf(acc[8+i]-bf16f(hi1));
      }
    }
  }

  // ---- Scores: St[mt_pk][nt_pq] = K @ Q^T ----
  f32x16 ST[2][2];
  #pragma unroll
  for (int nt=0;nt<2;nt++){
    short8 qh[4], ql[4];
    #pragma unroll
    for (int kt=0;kt<4;kt++){
      qh[kt] = QBlds[wvi][kt*2+nt][lane];
      ql[kt] = QBlds[wvi][8+kt*2+nt][lane];
    }
    #pragma unroll
    for (int mt=0;mt<2;mt++){
      f32x16 acc;
      #pragma unroll
      for (int r=0;r<16;r++) acc[r]=0.f;
      #pragma unroll
      for (int kt=0;kt<4;kt++){
        acc = __builtin_amdgcn_mfma_f32_32x32x16_bf16(KAh[mt][kt], qh[kt], acc, 0,0,0);
        acc = __builtin_amdgcn_mfma_f32_32x32x16_bf16(KAh[mt][kt], ql[kt], acc, 0,0,0);
        acc = __builtin_amdgcn_mfma_f32_32x32x16_bf16(KAl[mt][kt], qh[kt], acc, 0,0,0);
      }
      ST[mt][nt] = acc;
    }
  }

  // ---- softmax over keys (rows p_k: in-lane regs across 2 mt-tiles + partner half) ----
  #pragma unroll
  for (int nt=0;nt<2;nt++){
    float mx = ST[0][nt][0];
    #pragma unroll
    for (int r=1;r<16;r++) mx = fmaxf(mx, ST[0][nt][r]);
    #pragma unroll
    for (int r=0;r<16;r++) mx = fmaxf(mx, ST[1][nt][r]);
    mx = fmaxf(mx, __shfl_xor(mx, 32));
    float sum = 0.f;
    #pragma unroll
    for (int mt=0;mt<2;mt++)
      #pragma unroll
      for (int r=0;r<16;r++){ float e = expf(ST[mt][nt][r]-mx); ST[mt][nt][r]=e; sum += e; }
    sum += __shfl_xor(sum, 32);
    float inv = 1.f/sum;
    #pragma unroll
    for (int mt=0;mt<2;mt++)
      #pragma unroll
      for (int r=0;r<16;r++) ST[mt][nt][r] *= inv;
  }

  // ---- P -> B-frags (plain bf16) ----
  short8 PB[4][2];
  #pragma unroll
  for (int mt=0;mt<2;mt++)
    #pragma unroll
    for (int nt=0;nt<2;nt++){
      #pragma unroll
      for (int i=0;i<8;i++){
        PB[2*mt  ][nt][i] = f2bf(ST[mt][nt][i]);
        PB[2*mt+1][nt][i] = f2bf(ST[mt][nt][8+i]);
      }
    }

  // ---- V1^T A-frags: lane = channel, k = pixel ----
  short8 VA[2][4];
  #pragma unroll
  for (int mt=0;mt<2;mt++){
    int c = (mt<<5) | l31;
    const float* vp = v + cbase + ((size_t)c<<16);
    const float* mTr = mrowT + (c<<6);
    #pragma unroll
    for (int kt=0;kt<4;kt++){
      float4 va = *(const float4*)&vp[((kt<<1)<<8) + (h<<2)];
      float4 vb2 = *(const float4*)&vp[(((kt<<1)|1)<<8) + (h<<2)];
      float4 ma = *(const float4*)&mTr[(kt<<4)+(h<<2)];
      float4 mb = *(const float4*)&mTr[(kt<<4)+(h<<2)+8];
      short8 f;
      f[0]=f2bf(va.x*ma.x); f[1]=f2bf(va.y*ma.y); f[2]=f2bf(va.z*ma.z); f[3]=f2bf(va.w*ma.w);
      f[4]=f2bf(vb2.x*mb.x); f[5]=f2bf(vb2.y*mb.y); f[6]=f2bf(vb2.z*mb.z); f[7]=f2bf(vb2.w*mb.w);
      VA[mt][kt]=f;
    }
  }

  // ---- F[mt_c][nt_pq] = V1^T @ P ----
  f32x16 FT[2][2];
  #pragma unroll
  for (int mt=0;mt<2;mt++)
    #pragma unroll
    for (int nt=0;nt<2;nt++){
      f32x16 acc;
      #pragma unroll
      for (int r=0;r<16;r++) acc[r]=0.f;
      #pragma unroll
      for (int kt=0;kt<4;kt++)
        acc = __builtin_amdgcn_mfma_f32_32x32x16_bf16(VA[mt][kt], PB[kt][nt], acc, 0,0,0);
      FT[mt][nt] = acc;
    }

  // ---- store: out = F + sa*(v - v*m) ----
  #pragma unroll
  for (int nt=0;nt<2;nt++){
    int p = (nt<<5) | l31;
    int po = ((p>>3)<<8) | (p&7);
    float sav = sa[(((size_t)b)<<16) + pix0 + po];
    const float* mr = mrow + (p<<6);
    #pragma unroll
    for (int mt=0;mt<2;mt++){
      #pragma unroll
      for (int rr=0;rr<4;rr++){
        float4 m4 = *(const float4*)&mr[(mt<<5)+(rr<<3)+(h<<2)];
        #pragma unroll
        for (int t=0;t<4;t++){
          int c = (mt<<5)+(rr<<3)+(h<<2)+t;
          size_t g = cbase + ((size_t)c<<16) + po;
          float vv = v[g];
          float mm = (t==0)?m4.x:(t==1)?m4.y:(t==2)?m4.z:m4.w;
          out[g] = FT[mt][nt][rr*4+t] + sav*vv*(1.f-mm);
        }
      }
    }
  }
}

// ---------- K7: fused dw3x3(pad1) -> dw3x3(dil2,pad2) -> gelu*ca + residual ----------
__global__ __launch_bounds__(256) void k7_fused(const float* __restrict__ in,
    const float* __restrict__ Wd1, const float* __restrict__ bd1,
    const float* __restrict__ Wd2, const float* __restrict__ bd2,
    const float* __restrict__ ca, float* __restrict__ dwout){
  __shared__ float IN[22*23];
  __shared__ float C1[20*21];
  int blk = blockIdx.x;
  int tx = blk & 15, ty = (blk>>4) & 15, ch = (blk>>8) & 63, b = blk>>14;
  int x0 = tx<<4, y0 = ty<<4;
  const float* plane = in + (((size_t)(b*64+ch))<<16);
  int tid = threadIdx.x;
  for (int e = tid; e < 484; e += 256){
    int r = e/22, cc = e - r*22;
    int y = y0 + r - 3, xx = x0 + cc - 3;
    float vv = 0.f;
    if ((unsigned)y < 256u && (unsigned)xx < 256u) vv = plane[(y<<8)+xx];
    IN[r*23+cc] = vv;
  }
  __syncthreads();
  float w1[9], w2[9];
  #pragma unroll
  for (int t=0;t<9;t++){ w1[t]=Wd1[ch*9+t]; w2[t]=Wd2[ch*9+t]; }
  float b1 = bd1[ch];
  for (int e = tid; e < 400; e += 256){
    int r = e/20, cc = e - r*20;
    int yc1 = y0 + r - 2, xc1 = x0 + cc - 2;
    float acc = 0.f;
    if ((unsigned)yc1 < 256u && (unsigned)xc1 < 256u){
      acc = b1;
      #pragma unroll
      for (int ky=0;ky<3;ky++)
        #pragma unroll
        for (int kx=0;kx<3;kx++)
          acc = fmaf(w1[ky*3+kx], IN[(r+ky)*23 + cc+kx], acc);
    }
    C1[r*21+cc] = acc;
  }
  __syncthreads();
  int px = tid & 15, py = tid >> 4;
  float acc = bd2[ch];
  #pragma unroll
  for (int ky=0;ky<3;ky++)
    #pragma unroll
    for (int kx=0;kx<3;kx++)
      acc = fmaf(w2[ky*3+kx], C1[(py+2*ky)*21 + px+2*kx], acc);
  float g = 0.5f*acc*(1.f + erff(acc*0.70710678118654752f));
  float resid = IN[(py+3)*23 + px+3];
  size_t o = (((size_t)(b*64+ch))<<16) + ((size_t)((y0+py)<<8)) + x0+px;
  dwout[o] = fmaf(g, ca[b*64+ch], resid);
}

// ---------- K7c: final 1x1 conv ----------
__global__ __launch_bounds__(256) void k7c_proj(const float* __restrict__ in,
    const float* __restrict__ WoT, const float* __restrict__ bo, float* __restrict__ out){
  int b = blockIdx.x >> 8;
  int hw = ((blockIdx.x & 255) << 8) | threadIdx.x;
  const float* pb = in + (((size_t)b)<<22) + hw;
  float acc[64];
  #pragma unroll
  for (int oc=0;oc<64;oc++) acc[oc]=bo[oc];
  for (int c=0;c<64;c++){
    float xv = pb[((size_t)c)<<16];
    const float* wrow = WoT + (c<<6);
    #pragma unroll
    for (int oc=0;oc<64;oc++) acc[oc] = fmaf(wrow[oc], xv, acc[oc]);
  }
  float* ob = out + (((size_t)b)<<22) + hw;
  #pragma unroll
  for (int oc=0;oc<64;oc++) ob[((size_t)oc)<<16] = acc[oc];
}

extern "C" void kernel_launch(void* const* d_in, const int* in_sizes, int n_in,
                              void* d_out, int out_size, void* d_ws, size_t ws_size,
                              hipStream_t stream) {
  const float* x    = (const float*)d_in[0];
  const float* Wv   = (const float*)d_in[1];
  const float* bv   = (const float*)d_in[2];
  const float* Wri  = (const float*)d_in[3];
  const float* bri  = (const float*)d_in[4];
  const float* Wrc  = (const float*)d_in[5];
  const float* brc  = (const float*)d_in[6];
  const float* ln_w = (const float*)d_in[7];
  const float* ln_b = (const float*)d_in[8];
  const float* Wca  = (const float*)d_in[9];
  const float* bca  = (const float*)d_in[10];
  const float* Wsa  = (const float*)d_in[11];
  const float* bsa  = (const float*)d_in[12];
  const float* Wm1  = (const float*)d_in[13];
  const float* bm1  = (const float*)d_in[14];
  const float* Wm2  = (const float*)d_in[15];
  const float* bm2  = (const float*)d_in[16];
  const float* Wq   = (const float*)d_in[17];
  const float* bq   = (const float*)d_in[18];
  const float* Wk   = (const float*)d_in[19];
  const float* bk   = (const float*)d_in[20];
  const float* Wd1  = (const float*)d_in[21];
  const float* bd1  = (const float*)d_in[22];
  const float* Wd2  = (const float*)d_in[23];
  const float* bd2  = (const float*)d_in[24];
  const float* Wo   = (const float*)d_in[25];
  const float* bo   = (const float*)d_in[26];
  float* out = (float*)d_out;

  float* ws = (float*)d_ws;
  float* v_buf   = ws;                    // 16777216
  float* out_buf = v_buf + 16777216;      // 16777216
  float* x_buf   = out_buf + 16777216;    // 4194304
  float* xm_buf  = x_buf + 4194304;       // 262144
  float* sa_buf  = xm_buf + 262144;       // 262144
  float* bsum    = sa_buf + 262144;       // 16384
  float* ca_buf  = bsum + 16384;          // 256
  float* var_buf = ca_buf + 256;          // 4096
  float* sel_buf = var_buf + 4096;        // 4096
  float* mrow1   = sel_buf + 4096;        // 2048
  float* mrow0   = mrow1 + 2048;          // 2048
  float* mask1   = mrow0 + 2048;          // 4096
  float* mask0   = mask1 + 4096;          // 4096
  float* mask1T  = mask0 + 4096;          // 4096
  float* mask0T  = mask1T + 4096;         // 4096
  float* WoT     = mask0T + 4096;         // 4096
  float* WT      = WoT + 4096;            // 6144
  float* WriE    = WT + 6144;             // 1024
  float* WrcE    = WriE + 1024;           // 1024
  float* briE    = WrcE + 1024;           // 16
  float* brcE    = briE + 16;             // 16
  short* WFrag   = (short*)(brcE + 16);   // 20480 shorts (10240 floats)
  float* dw_buf  = v_buf;                 // reuse: v dead after k6

  k0_combine<<<4,256,0,stream>>>(Wv,bv,Wri,bri,Wrc,brc,WriE,briE,WrcE,brcE);
  k_prep<<<24,256,0,stream>>>(Wq,Wk,Wo,Wv,WriE,WrcE,bq,bk,WoT,WT,WFrag);
  k_premask1<<<2048,256,0,stream>>>(Wm1,bm1,mrow1,mrow0);
  k_premask2<<<4096,256,0,stream>>>(Wm2,bm2,mrow1,mrow0,mask1,mask0,mask1T,mask0T);
  k1_pw<<<1024,256,0,stream>>>(x,WT,bv,briE,brcE,ln_w,ln_b,v_buf,x_buf,xm_buf,bsum);
  k2_sa<<<1024,256,0,stream>>>(x_buf,Wsa,bsa,sa_buf);
  k3_ca<<<1,256,0,stream>>>(bsum,Wca,bca,ca_buf);
  k4a_var<<<16,256,0,stream>>>(xm_buf,var_buf);
  k4b_sel<<<4,1024,0,stream>>>(var_buf,sel_buf);
  k6_attn<<<1024,256,0,stream>>>(x,v_buf,sa_buf,sel_buf,mask1,mask0,mask1T,mask0T,WFrag,out_buf);
  k7_fused<<<65536,256,0,stream>>>(out_buf,Wd1,bd1,Wd2,bd2,ca_buf,dw_buf);
  k7c_proj<<<1024,256,0,stream>>>(dw_buf,WoT,bo,out);
}

// Round 6
// 393.042 us; speedup vs baseline: 2.1530x; 1.0012x over previous
//
#include <hip/hip_runtime.h>
#include <hip/hip_bf16.h>
#include <math.h>

typedef __attribute__((ext_vector_type(8))) short short8;
typedef __attribute__((ext_vector_type(16))) float f32x16;

__device__ __forceinline__ float lrelu(float x){ return x >= 0.f ? x : 0.1f*x; }
__device__ __forceinline__ float sigmoidf(float x){ return 1.f/(1.f+expf(-x)); }
__device__ __forceinline__ short f2bf(float f){
  __hip_bfloat16 hb = __float2bfloat16(f);
  return *reinterpret_cast<short*>(&hb);
}
__device__ __forceinline__ float bf16f(short s){
  return __uint_as_float(((unsigned)(unsigned short)s)<<16);
}

// WFrag frag index: (((w*2+part)*2+mt)*4+kt)*512 + lane*8   (w: 0=Wq 1=Wk 2=Wo)
#define WF(w,part,mt,kt) ((((w)*8 + (part)*4 + (mt)*... 0)
#undef WF
__device__ __forceinline__ int WFofs(int w,int part,int mt,int kt){
  return (((w*2+part)*2+mt)*4+kt)*512;
}

// ---------- K0: effective weights WriE = Wri@Wv, WrcE = Wrc@Wv, biases ----------
__global__ void k0_combine(const float* __restrict__ Wv, const float* __restrict__ bv,
                           const float* __restrict__ Wri, const float* __restrict__ bri,
                           const float* __restrict__ Wrc, const float* __restrict__ brc,
                           float* __restrict__ WriE, float* __restrict__ briE,
                           float* __restrict__ WrcE, float* __restrict__ brcE){
  int idx = blockIdx.x*256 + threadIdx.x;
  if (idx < 1024){
    int j = idx>>6, c = idx&63;
    float s1=0.f, s2=0.f;
    for (int k=0;k<64;k++){ s1 = fmaf(Wri[j*64+k], Wv[k*64+c], s1); s2 = fmaf(Wrc[j*64+k], Wv[k*64+c], s2); }
    WriE[idx]=s1; WrcE[idx]=s2;
  }
  if (idx < 16){
    float s1=bri[idx], s2=brc[idx];
    for (int k=0;k<64;k++){ s1 = fmaf(Wri[idx*64+k], bv[k], s1); s2 = fmaf(Wrc[idx*64+k], bv[k], s2); }
    briE[idx]=s1; brcE[idx]=s2;
  }
}

// ---------- prep: WT blob + MFMA W-frag blob (Wq/Wk/Wo, hi/lo) ----------
__global__ void k_prep(const float* __restrict__ Wq, const float* __restrict__ Wk,
                       const float* __restrict__ Wo, const float* __restrict__ Wv,
                       const float* __restrict__ WriE, const float* __restrict__ WrcE,
                       float* __restrict__ WT, short* __restrict__ WFrag){
  int idx = blockIdx.x*256 + threadIdx.x;
  if (idx < 4096){
    int oc = idx>>6, c = idx&63;
    WT[c*96 + oc] = Wv[idx];
  } else if (idx < 6144){
    int t = idx - 4096;
    int j = (t>>6) & 15, c = t & 63;
    if (t < 1024) WT[c*96 + 64 + j] = WriE[j*64+c];
    else          WT[c*96 + 80 + j] = WrcE[j*64+c];
  }
  if (idx < 3072){
    int w = idx>>10, rem = idx&1023;
    int part = rem>>9, mt = (rem>>8)&1, kt = (rem>>6)&3, lane = rem&63;
    const float* W = (w==0)?Wq:((w==1)?Wk:Wo);
    int j = (mt<<5)|(lane&31);
    int hh = lane>>5;
    short8 frag;
    #pragma unroll
    for (int i=0;i<8;i++){
      int kl = (hh<<2) + (i&3) + ((i>>2)<<3);
      float val = W[j*64 + (kt<<4) + kl];
      short hi = f2bf(val);
      frag[i] = part ? f2bf(val - bf16f(hi)) : hi;
    }
    *(short8*)&WFrag[WFofs(w,part,mt,kt) + (lane<<3)] = frag;
  }
}

// ---------- premask 1 ----------
__global__ void k_premask1(const float* __restrict__ Wm1, const float* __restrict__ bm1,
                           float* __restrict__ mrow1, float* __restrict__ mrow0){
  __shared__ float red[256];
  int j = blockIdx.x, tid = threadIdx.x;
  const float* row = Wm1 + (size_t)j*4096;
  float s=0.f;
  for (int e=tid;e<4096;e+=256) s += row[e];
  red[tid]=s; __syncthreads();
  for (int o=128;o;o>>=1){ if (tid<o) red[tid]+=red[tid+o]; __syncthreads(); }
  if (tid==0){
    float t = red[0]+bm1[j];
    mrow1[j] = lrelu(t);
    mrow0[j] = lrelu(bm1[j]);
  }
}

// ---------- premask 2 (+ transposed copies) ----------
__global__ void k_premask2(const float* __restrict__ Wm2, const float* __restrict__ bm2,
                           const float* __restrict__ mrow1, const float* __restrict__ mrow0,
                           float* __restrict__ mask1, float* __restrict__ mask0,
                           float* __restrict__ mask1T, float* __restrict__ mask0T){
  __shared__ float r1[256], r0[256];
  int e = blockIdx.x, tid = threadIdx.x;
  const float* row = Wm2 + (size_t)e*2048;
  float s1=0.f, s0=0.f;
  for (int j=tid;j<2048;j+=256){ float wv=row[j]; s1 = fmaf(wv, mrow1[j], s1); s0 = fmaf(wv, mrow0[j], s0); }
  r1[tid]=s1; r0[tid]=s0; __syncthreads();
  for (int o=128;o;o>>=1){ if (tid<o){ r1[tid]+=r1[tid+o]; r0[tid]+=r0[tid+o]; } __syncthreads(); }
  if (tid==0){
    float m1 = r1[0]+bm2[e], m0 = r0[0]+bm2[e];
    mask1[e]=m1; mask0[e]=m0;
    int p = e>>6, c = e&63;
    mask1T[(c<<6)|p]=m1; mask0T[(c<<6)|p]=m0;
  }
}

// ---------- K1: per-pixel v, xm, x_, block channel-sums ----------
__global__ __launch_bounds__(256) void k1_pw(
    const float* __restrict__ x, const float* __restrict__ WT,
    const float* __restrict__ bv,
    const float* __restrict__ briE, const float* __restrict__ brcE,
    const float* __restrict__ ln_w, const float* __restrict__ ln_b,
    float* __restrict__ v, float* __restrict__ x_, float* __restrict__ xm,
    float* __restrict__ bsum){
  __shared__ float wred[4][16];
  int tid = threadIdx.x;
  int b = blockIdx.x >> 8;
  int hw = ((blockIdx.x & 255) << 8) | tid;
  const float* xb = x + (((size_t)b)<<22) + hw;
  float acc[64], r1[16], rc[16];
  #pragma unroll
  for (int oc=0;oc<64;oc++) acc[oc]=0.f;
  #pragma unroll
  for (int j=0;j<16;j++){ r1[j]=0.f; rc[j]=0.f; }
  for (int c=0;c<64;c++){
    float xv = xb[((size_t)c)<<16];
    const float* wrow = WT + c*96;
    #pragma unroll
    for (int oc=0;oc<64;oc++) acc[oc] = fmaf(wrow[oc], xv, acc[oc]);
    #pragma unroll
    for (int j=0;j<16;j++){ r1[j] = fmaf(wrow[64+j], xv, r1[j]); rc[j] = fmaf(wrow[80+j], xv, rc[j]); }
  }
  float* vb = v + (((size_t)b)<<22) + hw;
  #pragma unroll
  for (int oc=0;oc<64;oc++) vb[((size_t)oc)<<16] = acc[oc] + bv[oc];
  float s1=0.f;
  #pragma unroll
  for (int j=0;j<16;j++){ float t = r1[j]+briE[j]; s1 += lrelu(t); }
  xm[(((size_t)b)<<16)+hw] = s1*(1.f/16.f);
  float u=0.f;
  #pragma unroll
  for (int j=0;j<16;j++){ rc[j] += brcE[j]; u += rc[j]; }
  u *= (1.f/16.f);
  float s2=0.f;
  #pragma unroll
  for (int j=0;j<16;j++){ float d = rc[j]-u; s2 += d*d; }
  float inv = 1.0f / sqrtf(s2*(1.f/16.f) + 1e-6f);
  float xs[16];
  #pragma unroll
  for (int j=0;j<16;j++){
    float t = (rc[j]-u)*inv*ln_w[j] + ln_b[j];
    t = lrelu(t);
    xs[j]=t;
    x_[(((size_t)(b*16+j))<<16)+hw] = t;
  }
  int lane = tid & 63, wv_ = tid >> 6;
  #pragma unroll
  for (int j=0;j<16;j++){
    float val = xs[j];
    for (int o=32;o;o>>=1) val += __shfl_down(val, o, 64);
    if (lane==0) wred[wv_][j]=val;
  }
  __syncthreads();
  if (tid<16) bsum[blockIdx.x*16+tid] = wred[0][tid]+wred[1][tid]+wred[2][tid]+wred[3][tid];
}

// ---------- K2: sa ----------
__global__ __launch_bounds__(256) void k2_sa(const float* __restrict__ x_,
    const float* __restrict__ Wsa, const float* __restrict__ bsa, float* __restrict__ sa){
  int idx = blockIdx.x*256 + threadIdx.x;
  int b = idx>>16; int hw = idx & 65535; int h = hw>>8, wcol = hw & 255;
  float acc = bsa[0];
  for (int ch=0; ch<16; ++ch){
    const float* plane = x_ + (((size_t)(b*16+ch))<<16);
    #pragma unroll
    for (int ky=0;ky<3;ky++){
      int y = h + ky - 1;
      if ((unsigned)y >= 256u) continue;
      #pragma unroll
      for (int kx=0;kx<3;kx++){
        int xx = wcol + kx - 1;
        if ((unsigned)xx >= 256u) continue;
        acc = fmaf(Wsa[ch*9+ky*3+kx], plane[(y<<8)+xx], acc);
      }
    }
  }
  sa[idx] = sigmoidf(acc);
}

// ---------- K3: ca ----------
__global__ void k3_ca(const float* __restrict__ bsum, const float* __restrict__ Wca,
                      const float* __restrict__ bca, float* __restrict__ ca){
  __shared__ float meanx[4][16];
  int tid = threadIdx.x;
  if (tid < 64){
    int b = tid>>4, j = tid&15;
    float s=0.f;
    for (int blk=0;blk<256;blk++) s += bsum[(b*256+blk)*16 + j];
    meanx[b][j] = s*(1.f/65536.f);
  }
  __syncthreads();
  int b = tid>>6, oc = tid&63;
  float a = bca[oc];
  #pragma unroll
  for (int j=0;j<16;j++) a = fmaf(Wca[oc*16+j], meanx[b][j], a);
  ca[tid] = sigmoidf(a);
}

// ---------- K4a: per-window variance ----------
__global__ void k4a_var(const float* __restrict__ xm, float* __restrict__ var){
  int t = blockIdx.x*256 + threadIdx.x;
  int b = t>>10, n = t&1023, wh = n>>5, ww = n&31;
  const float* base = xm + (((size_t)b)<<16) + (wh<<11) + (ww<<3);
  float s=0.f;
  #pragma unroll
  for (int dh=0;dh<8;dh++){
    #pragma unroll
    for (int dw=0;dw<8;dw++) s += base[(dh<<8)+dw];
  }
  float mean = s*(1.f/64.f);
  float ss=0.f;
  #pragma unroll
  for (int dh=0;dh<8;dh++){
    #pragma unroll
    for (int dw=0;dw<8;dw++){ float d = base[(dh<<8)+dw]-mean; ss += d*d; }
  }
  var[t] = ss*(1.f/63.f);
}

// ---------- K4b: rank -> sel ----------
__global__ __launch_bounds__(1024) void k4b_sel(const float* __restrict__ var, float* __restrict__ sel){
  __shared__ float vs[1024];
  int b = blockIdx.x, tid = threadIdx.x;
  float mine = var[b*1024+tid];
  vs[tid]=mine; __syncthreads();
  int rank=0;
  for (int j=0;j<1024;j++){
    float o = vs[j];
    rank += (o < mine) || (o == mine && j < tid);
  }
  sel[b*1024+tid] = (rank >= 512) ? 1.f : 0.f;
}

// ---------- K6 v3: 2 waves per window, MFMA bf16 hi/lo, no Q-LDS ----------
// Wave owns 32 pixels (half ht). KA frags exchanged via 32KB LDS, one barrier.
__global__ __launch_bounds__(256, 3) void k6_attn(
    const float* __restrict__ x, const float* __restrict__ v, const float* __restrict__ sa,
    const float* __restrict__ sel,
    const float* __restrict__ mask1, const float* __restrict__ mask0,
    const float* __restrict__ mask1T, const float* __restrict__ mask0T,
    const short* __restrict__ WFrag,
    const float* __restrict__ bq, const float* __restrict__ bk,
    float* __restrict__ out){
  __shared__ short8 KAlds[2][2][8][64];   // [win][keyhalf][hi0-3|lo4-7][lane]
  int tid = threadIdx.x;
  int lane = tid & 63, wvi = tid >> 6;
  int wi = wvi >> 1, ht = wvi & 1;
  int l31 = lane & 31, h = lane >> 5;
  int bid = blockIdx.x;
  int blk = ((bid & 7) << 8) | (bid >> 3);      // 2048 = 8*256 bijective XCD swizzle
  int wg = (blk << 1) | wi;
  int b = wg >> 10, n = wg & 1023;
  int pix0 = ((n >> 5) << 11) | ((n & 31) << 3);
  bool sel1 = sel[wg] > 0.5f;
  const float* mrow  = sel1 ? mask1  : mask0;
  const float* mrowT = sel1 ? mask1T : mask0T;
  size_t cbase = (((size_t)b) << 22) + pix0;

  // ---- own 32 pixels: masked-x B-frags (hi/lo) ----
  int p = (ht<<5) | l31;
  int po = ((p>>3)<<8) | (p&7);
  size_t gp = cbase + po;
  const float* mr = mrow + (p<<6);
  short8 XBh[4], XBl[4];
  #pragma unroll
  for (int kt=0;kt<4;kt++){
    float4 ma = *(const float4*)&mr[(kt<<4)+(h<<2)];
    float4 mb = *(const float4*)&mr[(kt<<4)+(h<<2)+8];
    float xv[8];
    #pragma unroll
    for (int i=0;i<8;i++){
      int c = (kt<<4) + (h<<2) + (i&3) + ((i>>2)<<3);
      xv[i] = x[gp + ((size_t)c<<16)];
    }
    xv[0]*=ma.x; xv[1]*=ma.y; xv[2]*=ma.z; xv[3]*=ma.w;
    xv[4]*=mb.x; xv[5]*=mb.y; xv[6]*=mb.z; xv[7]*=mb.w;
    short8 fh, fl;
    #pragma unroll
    for (int i=0;i<8;i++){
      short hi = f2bf(xv[i]); fh[i]=hi; fl[i]=f2bf(xv[i]-bf16f(hi));
    }
    XBh[kt]=fh; XBl[kt]=fl;
  }

  // ---- Q projection -> QB frags (in-lane from C-tile) ----
  short8 QBh[4], QBl[4];
  #pragma unroll
  for (int mt=0;mt<2;mt++){
    f32x16 acc;
    #pragma unroll
    for (int r=0;r<16;r++) acc[r]=0.f;
    #pragma unroll
    for (int kt=0;kt<4;kt++){
      short8 WAh = *(const short8*)&WFrag[WFofs(0,0,mt,kt) + (lane<<3)];
      short8 WAl = *(const short8*)&WFrag[WFofs(0,1,mt,kt) + (lane<<3)];
      acc = __builtin_amdgcn_mfma_f32_32x32x16_bf16(WAh, XBh[kt], acc, 0,0,0);
      acc = __builtin_amdgcn_mfma_f32_32x32x16_bf16(WAh, XBl[kt], acc, 0,0,0);
      acc = __builtin_amdgcn_mfma_f32_32x32x16_bf16(WAl, XBh[kt], acc, 0,0,0);
    }
    #pragma unroll
    for (int rr=0;rr<4;rr++){
      float4 b4 = *(const float4*)&bq[(mt<<5)+(rr<<3)+(h<<2)];
      acc[4*rr+0]+=b4.x; acc[4*rr+1]+=b4.y; acc[4*rr+2]+=b4.z; acc[4*rr+3]+=b4.w;
    }
    #pragma unroll
    for (int kk=0;kk<2;kk++){
      short8 fh, fl;
      #pragma unroll
      for (int i=0;i<8;i++){
        float vv = acc[8*kk+i];
        short hi = f2bf(vv); fh[i]=hi; fl[i]=f2bf(vv-bf16f(hi));
      }
      QBh[2*mt+kk]=fh; QBl[2*mt+kk]=fl;
    }
  }

  // ---- K projection -> KA frags -> LDS ----
  #pragma unroll
  for (int mt=0;mt<2;mt++){
    f32x16 acc;
    #pragma unroll
    for (int r=0;r<16;r++) acc[r]=0.f;
    #pragma unroll
    for (int kt=0;kt<4;kt++){
      short8 WAh = *(const short8*)&WFrag[WFofs(1,0,mt,kt) + (lane<<3)];
      short8 WAl = *(const short8*)&WFrag[WFofs(1,1,mt,kt) + (lane<<3)];
      acc = __builtin_amdgcn_mfma_f32_32x32x16_bf16(WAh, XBh[kt], acc, 0,0,0);
      acc = __builtin_amdgcn_mfma_f32_32x32x16_bf16(WAh, XBl[kt], acc, 0,0,0);
      acc = __builtin_amdgcn_mfma_f32_32x32x16_bf16(WAl, XBh[kt], acc, 0,0,0);
    }
    #pragma unroll
    for (int rr=0;rr<4;rr++){
      float4 b4 = *(const float4*)&bk[(mt<<5)+(rr<<3)+(h<<2)];
      acc[4*rr+0]+=b4.x; acc[4*rr+1]+=b4.y; acc[4*rr+2]+=b4.z; acc[4*rr+3]+=b4.w;
    }
    #pragma unroll
    for (int kk=0;kk<2;kk++){
      short8 fh, fl;
      #pragma unroll
      for (int i=0;i<8;i++){
        float vv = acc[8*kk+i];
        short hi = f2bf(vv); fh[i]=hi; fl[i]=f2bf(vv-bf16f(hi));
      }
      KAlds[wi][ht][2*mt+kk][lane]   = fh;
      KAlds[wi][ht][4+2*mt+kk][lane] = fl;
    }
  }
  __syncthreads();

  // ---- S[keyhalf mt][own queries] = K @ Q^T ----
  f32x16 ST[2];
  #pragma unroll
  for (int mt=0;mt<2;mt++){
    f32x16 acc;
    #pragma unroll
    for (int r=0;r<16;r++) acc[r]=0.f;
    #pragma unroll
    for (int kt=0;kt<4;kt++){
      short8 kh = KAlds[wi][mt][kt][lane];
      short8 kl = KAlds[wi][mt][4+kt][lane];
      acc = __builtin_amdgcn_mfma_f32_32x32x16_bf16(kh, QBh[kt], acc, 0,0,0);
      acc = __builtin_amdgcn_mfma_f32_32x32x16_bf16(kh, QBl[kt], acc, 0,0,0);
      acc = __builtin_amdgcn_mfma_f32_32x32x16_bf16(kl, QBh[kt], acc, 0,0,0);
    }
    ST[mt] = acc;
  }

  // ---- softmax over keys (32 in-lane regs + partner h-half) ----
  float mx = ST[0][0];
  #pragma unroll
  for (int r=1;r<16;r++) mx = fmaxf(mx, ST[0][r]);
  #pragma unroll
  for (int r=0;r<16;r++) mx = fmaxf(mx, ST[1][r]);
  mx = fmaxf(mx, __shfl_xor(mx, 32));
  float sum = 0.f;
  #pragma unroll
  for (int mt=0;mt<2;mt++)
    #pragma unroll
    for (int r=0;r<16;r++){ float e = expf(ST[mt][r]-mx); ST[mt][r]=e; sum += e; }
  sum += __shfl_xor(sum, 32);
  float inv = 1.f/sum;

  // ---- P -> B-frags (bf16) ----
  short8 PB[4];
  #pragma unroll
  for (int mt=0;mt<2;mt++)
    #pragma unroll
    for (int kk=0;kk<2;kk++){
      short8 f;
      #pragma unroll
      for (int i=0;i<8;i++) f[i] = f2bf(ST[mt][8*kk+i]*inv);
      PB[2*mt+kk]=f;
    }

  float sav = sa[(((size_t)b)<<16) + pix0 + po];

  // ---- F[c-half][own queries] = V1^T @ P ; store with skip ----
  #pragma unroll
  for (int mtc=0;mtc<2;mtc++){
    int c0 = (mtc<<5);
    int cl = c0 | l31;
    const float* vp = v + cbase + ((size_t)cl<<16);
    const float* mTr = mrowT + (cl<<6);
    f32x16 acc;
    #pragma unroll
    for (int r=0;r<16;r++) acc[r]=0.f;
    #pragma unroll
    for (int kt=0;kt<4;kt++){
      float4 va  = *(const float4*)&vp[((kt<<1)<<8) + (h<<2)];
      float4 vb2 = *(const float4*)&vp[(((kt<<1)|1)<<8) + (h<<2)];
      float4 ma = *(const float4*)&mTr[(kt<<4)+(h<<2)];
      float4 mb = *(const float4*)&mTr[(kt<<4)+(h<<2)+8];
      short8 f;
      f[0]=f2bf(va.x*ma.x); f[1]=f2bf(va.y*ma.y); f[2]=f2bf(va.z*ma.z); f[3]=f2bf(va.w*ma.w);
      f[4]=f2bf(vb2.x*mb.x); f[5]=f2bf(vb2.y*mb.y); f[6]=f2bf(vb2.z*mb.z); f[7]=f2bf(vb2.w*mb.w);
      acc = __builtin_amdgcn_mfma_f32_32x32x16_bf16(f, PB[kt], acc, 0,0,0);
    }
    #pragma unroll
    for (int rr=0;rr<4;rr++){
      float4 m4 = *(const float4*)&mr[c0+(rr<<3)+(h<<2)];
      #pragma unroll
      for (int t=0;t<4;t++){
        int c = c0 + (rr<<3) + (h<<2) + t;
        size_t g = cbase + ((size_t)c<<16) + po;
        float vv = v[g];
        float mm = (t==0)?m4.x:(t==1)?m4.y:(t==2)?m4.z:m4.w;
        out[g] = acc[4*rr+t] + sav*vv*(1.f-mm);
      }
    }
  }
}

// ---------- K7: fused dw3x3(pad1) -> dw3x3(dil2,pad2) -> gelu*ca + residual ----------
__global__ __launch_bounds__(256) void k7_fused(const float* __restrict__ in,
    const float* __restrict__ Wd1, const float* __restrict__ bd1,
    const float* __restrict__ Wd2, const float* __restrict__ bd2,
    const float* __restrict__ ca, float* __restrict__ dwout){
  __shared__ float IN[22*23];
  __shared__ float C1[20*21];
  int blk = blockIdx.x;
  int tx = blk & 15, ty = (blk>>4) & 15, ch = (blk>>8) & 63, b = blk>>14;
  int x0 = tx<<4, y0 = ty<<4;
  const float* plane = in + (((size_t)(b*64+ch))<<16);
  int tid = threadIdx.x;
  for (int e = tid; e < 484; e += 256){
    int r = e/22, cc = e - r*22;
    int y = y0 + r - 3, xx = x0 + cc - 3;
    float vv = 0.f;
    if ((unsigned)y < 256u && (unsigned)xx < 256u) vv = plane[(y<<8)+xx];
    IN[r*23+cc] = vv;
  }
  __syncthreads();
  float w1[9], w2[9];
  #pragma unroll
  for (int t=0;t<9;t++){ w1[t]=Wd1[ch*9+t]; w2[t]=Wd2[ch*9+t]; }
  float b1 = bd1[ch];
  for (int e = tid; e < 400; e += 256){
    int r = e/20, cc = e - r*20;
    int yc1 = y0 + r - 2, xc1 = x0 + cc - 2;
    float acc = 0.f;
    if ((unsigned)yc1 < 256u && (unsigned)xc1 < 256u){
      acc = b1;
      #pragma unroll
      for (int ky=0;ky<3;ky++)
        #pragma unroll
        for (int kx=0;kx<3;kx++)
          acc = fmaf(w1[ky*3+kx], IN[(r+ky)*23 + cc+kx], acc);
    }
    C1[r*21+cc] = acc;
  }
  __syncthreads();
  int px = tid & 15, py = tid >> 4;
  float acc = bd2[ch];
  #pragma unroll
  for (int ky=0;ky<3;ky++)
    #pragma unroll
    for (int kx=0;kx<3;kx++)
      acc = fmaf(w2[ky*3+kx], C1[(py+2*ky)*21 + px+2*kx], acc);
  float g = 0.5f*acc*(1.f + erff(acc*0.70710678118654752f));
  float resid = IN[(py+3)*23 + px+3];
  size_t o = (((size_t)(b*64+ch))<<16) + ((size_t)((y0+py)<<8)) + x0+px;
  dwout[o] = fmaf(g, ca[b*64+ch], resid);
}

// ---------- K7c: final 1x1 conv via MFMA (hi/lo 3-product) ----------
__global__ __launch_bounds__(256, 3) void k7c_proj(const float* __restrict__ in,
    const short* __restrict__ WFrag, const float* __restrict__ bo,
    float* __restrict__ out){
  int tid = threadIdx.x;
  int lane = tid & 63, wvi = tid >> 6;
  int l31 = lane & 31, h = lane >> 5;
  int blk = blockIdx.x;
  int b = blk >> 8;
  int hw0 = ((blk & 255) << 8) | (wvi << 6);
  size_t base = ((size_t)b) << 22;
  #pragma unroll
  for (int nt=0;nt<2;nt++){
    int px = hw0 | (nt<<5) | l31;
    short8 XH[4], XL[4];
    #pragma unroll
    for (int kt=0;kt<4;kt++){
      float xv[8];
      #pragma unroll
      for (int i=0;i<8;i++){
        int c = (kt<<4) + (h<<2) + (i&3) + ((i>>2)<<3);
        xv[i] = in[base + ((size_t)c<<16) + px];
      }
      short8 fh, fl;
      #pragma unroll
      for (int i=0;i<8;i++){
        short hi = f2bf(xv[i]); fh[i]=hi; fl[i]=f2bf(xv[i]-bf16f(hi));
      }
      XH[kt]=fh; XL[kt]=fl;
    }
    #pragma unroll
    for (int mt=0;mt<2;mt++){
      f32x16 acc;
      #pragma unroll
      for (int r=0;r<16;r++) acc[r]=0.f;
      #pragma unroll
      for (int kt=0;kt<4;kt++){
        short8 WAh = *(const short8*)&WFrag[WFofs(2,0,mt,kt) + (lane<<3)];
        short8 WAl = *(const short8*)&WFrag[WFofs(2,1,mt,kt) + (lane<<3)];
        acc = __builtin_amdgcn_mfma_f32_32x32x16_bf16(WAh, XH[kt], acc, 0,0,0);
        acc = __builtin_amdgcn_mfma_f32_32x32x16_bf16(WAh, XL[kt], acc, 0,0,0);
        acc = __builtin_amdgcn_mfma_f32_32x32x16_bf16(WAl, XH[kt], acc, 0,0,0);
      }
      #pragma unroll
      for (int rr=0;rr<4;rr++){
        float4 b4 = *(const float4*)&bo[(mt<<5)+(rr<<3)+(h<<2)];
        #pragma unroll
        for (int t=0;t<4;t++){
          int oc = (mt<<5) + (rr<<3) + (h<<2) + t;
          float bb = (t==0)?b4.x:(t==1)?b4.y:(t==2)?b4.z:b4.w;
          out[base + ((size_t)oc<<16) + px] = acc[4*rr+t] + bb;
        }
      }
    }
  }
}

extern "C" void kernel_launch(void* const* d_in, const int* in_sizes, int n_in,
                              void* d_out, int out_size, void* d_ws, size_t ws_size,
                              hipStream_t stream) {
  const float* x    = (const float*)d_in[0];
  const float* Wv   = (const float*)d_in[1];
  const float* bv   = (const float*)d_in[2];
  const float* Wri  = (const float*)d_in[3];
  const float* bri  = (const float*)d_in[4];
  const float* Wrc  = (const float*)d_in[5];
  const float* brc  = (const float*)d_in[6];
  const float* ln_w = (const float*)d_in[7];
  const float* ln_b = (const float*)d_in[8];
  const float* Wca  = (const float*)d_in[9];
  const float* bca  = (const float*)d_in[10];
  const float* Wsa  = (const float*)d_in[11];
  const float* bsa  = (const float*)d_in[12];
  const float* Wm1  = (const float*)d_in[13];
  const float* bm1  = (const float*)d_in[14];
  const float* Wm2  = (const float*)d_in[15];
  const float* bm2  = (const float*)d_in[16];
  const float* Wq   = (const float*)d_in[17];
  const float* bq   = (const float*)d_in[18];
  const float* Wk   = (const float*)d_in[19];
  const float* bk   = (const float*)d_in[20];
  const float* Wd1  = (const float*)d_in[21];
  const float* bd1  = (const float*)d_in[22];
  const float* Wd2  = (const float*)d_in[23];
  const float* bd2  = (const float*)d_in[24];
  const float* Wo   = (const float*)d_in[25];
  const float* bo   = (const float*)d_in[26];
  float* out = (float*)d_out;

  float* ws = (float*)d_ws;
  float* v_buf   = ws;                    // 16777216
  float* out_buf = v_buf + 16777216;      // 16777216
  float* x_buf   = out_buf + 16777216;    // 4194304
  float* xm_buf  = x_buf + 4194304;       // 262144
  float* sa_buf  = xm_buf + 262144;       // 262144
  float* bsum    = sa_buf + 262144;       // 16384
  float* ca_buf  = bsum + 16384;          // 256
  float* var_buf = ca_buf + 256;          // 4096
  float* sel_buf = var_buf + 4096;        // 4096
  float* mrow1   = sel_buf + 4096;        // 2048
  float* mrow0   = mrow1 + 2048;          // 2048
  float* mask1   = mrow0 + 2048;          // 4096
  float* mask0   = mask1 + 4096;          // 4096
  float* mask1T  = mask0 + 4096;          // 4096
  float* mask0T  = mask1T + 4096;         // 4096
  float* WT      = mask0T + 4096;         // 6144
  float* WriE    = WT + 6144;             // 1024
  float* WrcE    = WriE + 1024;           // 1024
  float* briE    = WrcE + 1024;           // 16
  float* brcE    = briE + 16;             // 16
  short* WFrag   = (short*)(brcE + 16);   // 24576 shorts (12288 floats)
  float* dw_buf  = v_buf;                 // reuse: v dead after k6

  k0_combine<<<4,256,0,stream>>>(Wv,bv,Wri,bri,Wrc,brc,WriE,briE,WrcE,brcE);
  k_prep<<<24,256,0,stream>>>(Wq,Wk,Wo,Wv,WriE,WrcE,WT,WFrag);
  k_premask1<<<2048,256,0,stream>>>(Wm1,bm1,mrow1,mrow0);
  k_premask2<<<4096,256,0,stream>>>(Wm2,bm2,mrow1,mrow0,mask1,mask0,mask1T,mask0T);
  k1_pw<<<1024,256,0,stream>>>(x,WT,bv,briE,brcE,ln_w,ln_b,v_buf,x_buf,xm_buf,bsum);
  k2_sa<<<1024,256,0,stream>>>(x_buf,Wsa,bsa,sa_buf);
  k3_ca<<<1,256,0,stream>>>(bsum,Wca,bca,ca_buf);
  k4a_var<<<16,256,0,stream>>>(xm_buf,var_buf);
  k4b_sel<<<4,1024,0,stream>>>(var_buf,sel_buf);
  k6_attn<<<2048,256,0,stream>>>(x,v_buf,sa_buf,sel_buf,mask1,mask0,mask1T,mask0T,WFrag,bq,bk,out_buf);
  k7_fused<<<65536,256,0,stream>>>(out_buf,Wd1,bd1,Wd2,bd2,ca_buf,dw_buf);
  k7c_proj<<<1024,256,0,stream>>>(dw_buf,WFrag,bo,out);
}